// Round 2
// baseline (1836.169 us; speedup 1.0000x reference)
//
#include <hip/hip_runtime.h>
#include <math.h>

#define FEAT 256
#define NHEAD 8
#define HD 32
#define NLAYERS 3
#define EHR_IN 498
#define MAXLEN 500
#define BATCH 16
#define CXR_IN 2048
#define FFDIM 1024
#define NROWS 32
#define TLEN 501

#define F_GELU 1
#define F_RESID 2
#define F_POSEMB 4

// ---------------------------------------------------------------------------
// Generic 64x64 tiled fp32 GEMM: C[z][m][n] = A[z][m][:K] @ B[:K][n] + epilogue
// Rows are ragged: only m < len(z) are computed/stored.
// lenMode 0: len = seq[z] (ehr projection, z = batch index)
// lenMode 1: len = (z&1) ? 1 : seq[z>>1] (token rows, z = sequence index)
// ---------------------------------------------------------------------------
__global__ __launch_bounds__(256) void gemm_frag(
    const float* __restrict__ A, int lda, long long aStrideZ, int Mrows,
    const float* __restrict__ Bw, int ldb, int K,
    float* __restrict__ C, int ldc, long long cStrideZ,
    const float* __restrict__ bias,
    const float* __restrict__ resid, long long resStrideZ,
    const float* __restrict__ modv, const float* __restrict__ posm,
    const int* __restrict__ seqlen, int lenMode, int flags)
{
    int z = blockIdx.z;
    int len = (lenMode == 0) ? seqlen[z] : ((z & 1) ? 1 : seqlen[z >> 1]);
    int m0 = blockIdx.x * 64;
    if (m0 >= len) return;
    int n0 = blockIdx.y * 64;

    const float* Az = A + (long long)z * aStrideZ;
    float* Cz = C + (long long)z * cStrideZ;

    __shared__ float As[16][68];   // [k][m], row stride 68 floats = 272B (16B aligned)
    __shared__ float Bs[16][68];   // [k][n]

    int tid = threadIdx.x;
    int tx = tid & 15, ty = tid >> 4;

    float acc[4][4];
#pragma unroll
    for (int i = 0; i < 4; i++)
#pragma unroll
        for (int j = 0; j < 4; j++) acc[i][j] = 0.f;

    int arow = m0 + (tid >> 2);     // A-load: row
    int ak   = (tid & 3) * 4;       // A-load: k offset within tile
    int am   = tid >> 2;
    int bk   = tid >> 4;            // B-load: k row within tile
    int bncol = n0 + (tid & 15) * 4;

    int nk = (K + 15) >> 4;
    for (int kt = 0; kt < nk; ++kt) {
        int k0 = kt << 4;
        // ---- stage A (transposed) ----
        float4 av = make_float4(0.f, 0.f, 0.f, 0.f);
        if (arow < Mrows) {
            int kk = k0 + ak;
            const float* p = Az + (long long)arow * lda;
            if (kk + 3 < K) {
                av = *(const float4*)(p + kk);
            } else {
                av.x = (kk + 0 < K) ? p[kk + 0] : 0.f;
                av.y = (kk + 1 < K) ? p[kk + 1] : 0.f;
                av.z = (kk + 2 < K) ? p[kk + 2] : 0.f;
                av.w = (kk + 3 < K) ? p[kk + 3] : 0.f;
            }
        }
        As[ak + 0][am] = av.x;
        As[ak + 1][am] = av.y;
        As[ak + 2][am] = av.z;
        As[ak + 3][am] = av.w;
        // ---- stage B ----
        float4 bv = make_float4(0.f, 0.f, 0.f, 0.f);
        int kb = k0 + bk;
        if (kb < K) bv = *(const float4*)(Bw + (long long)kb * ldb + bncol);
        *(float4*)&Bs[bk][(tid & 15) * 4] = bv;

        __syncthreads();
#pragma unroll
        for (int kk = 0; kk < 16; ++kk) {
            float4 a = *(const float4*)&As[kk][ty * 4];
            float4 b = *(const float4*)&Bs[kk][tx * 4];
            acc[0][0] += a.x * b.x; acc[0][1] += a.x * b.y; acc[0][2] += a.x * b.z; acc[0][3] += a.x * b.w;
            acc[1][0] += a.y * b.x; acc[1][1] += a.y * b.y; acc[1][2] += a.y * b.z; acc[1][3] += a.y * b.w;
            acc[2][0] += a.z * b.x; acc[2][1] += a.z * b.y; acc[2][2] += a.z * b.z; acc[2][3] += a.z * b.w;
            acc[3][0] += a.w * b.x; acc[3][1] += a.w * b.y; acc[3][2] += a.w * b.z; acc[3][3] += a.w * b.w;
        }
        __syncthreads();
    }

#pragma unroll
    for (int i = 0; i < 4; i++) {
        int gm = m0 + ty * 4 + i;
        if (gm >= len) continue;
#pragma unroll
        for (int j = 0; j < 4; j++) {
            int gn = n0 + tx * 4 + j;
            float v = acc[i][j] + bias[gn];
            if (flags & F_POSEMB) v += modv[gn] + posm[(long long)gm * FEAT + gn];
            if (flags & F_RESID)  v += resid[(long long)z * resStrideZ + (long long)gm * ldc + gn];
            if (flags & F_GELU)   v = 0.5f * v * (1.f + erff(v * 0.70710678118654752f));
            Cz[(long long)gm * ldc + gn] = v;
        }
    }
}

// ---------------------------------------------------------------------------
// CXR projection: x[2b+1][0][:] = cxr[b] @ cxr_w + cxr_b + mod[1] + pos[0]
// ---------------------------------------------------------------------------
__global__ __launch_bounds__(256) void cxr_proj(
    const float* __restrict__ cxr, const float* __restrict__ W,
    const float* __restrict__ b, const float* __restrict__ mod1,
    const float* __restrict__ pos0, float* __restrict__ x)
{
    int bb = blockIdx.x;
    int j = threadIdx.x;
    const float* xrow = cxr + (long long)bb * CXR_IN;
    float acc = 0.f;
#pragma unroll 8
    for (int k = 0; k < CXR_IN; ++k) acc += xrow[k] * W[(long long)k * FEAT + j];
    float v = acc + b[j] + mod1[j] + pos0[j];
    x[((long long)(2 * bb + 1) * TLEN) * FEAT + j] = v;
}

// ---------------------------------------------------------------------------
// Flash-style attention: 1 thread = 1 query row; K/V tiles staged in LDS;
// chunked online softmax. Only computes q < len, keys < len (mask-equivalent:
// exp(-1e9 - m) == 0 in fp32).
// ---------------------------------------------------------------------------
__global__ __launch_bounds__(128) void attn_kernel(
    const float* __restrict__ qkv, float* __restrict__ o,
    const int* __restrict__ seqlen)
{
    int n = blockIdx.z, h = blockIdx.y, qt = blockIdx.x;
    int len = (n & 1) ? 1 : seqlen[n >> 1];
    int q0 = qt * 128;
    if (q0 >= len) return;
    int tid = threadIdx.x;
    int qi = q0 + tid;
    bool act = qi < len;

    const float* base = qkv + (long long)n * TLEN * 768;
    const float* qrow = base + (long long)(act ? qi : q0) * 768 + h * HD;
    float qreg[32];
#pragma unroll
    for (int d = 0; d < 32; d += 4) {
        float4 v = *(const float4*)(qrow + d);
        qreg[d] = v.x; qreg[d + 1] = v.y; qreg[d + 2] = v.z; qreg[d + 3] = v.w;
    }

    const float scale = 0.17677669529663687f; // 1/sqrt(32)
    float m = -1e30f, l = 0.f;
    float acc[32];
#pragma unroll
    for (int d = 0; d < 32; d++) acc[d] = 0.f;

    __shared__ float Ks[128][32];
    __shared__ float Vs[128][32];

    for (int k0 = 0; k0 < len; k0 += 128) {
        int kend = min(128, len - k0);
        if (tid < kend) {
            const float* krow = base + (long long)(k0 + tid) * 768 + 256 + h * HD;
#pragma unroll
            for (int d = 0; d < 32; d += 4) {
                *(float4*)&Ks[tid][d] = *(const float4*)(krow + d);
                *(float4*)&Vs[tid][d] = *(const float4*)(krow + 256 + d);
            }
        }
        __syncthreads();

        for (int kk = 0; kk < kend; kk += 16) {
            float s[16];
#pragma unroll
            for (int j = 0; j < 16; ++j) {
                const float* kr = &Ks[kk + j][0];
                float d0 = 0.f;
#pragma unroll
                for (int d = 0; d < 32; d += 4) {
                    float4 kv = *(const float4*)(kr + d);
                    d0 += qreg[d] * kv.x + qreg[d + 1] * kv.y
                        + qreg[d + 2] * kv.z + qreg[d + 3] * kv.w;
                }
                s[j] = (kk + j < kend) ? d0 * scale : -1e30f;
            }
            float cm = m;
#pragma unroll
            for (int j = 0; j < 16; ++j) cm = fmaxf(cm, s[j]);
            if (cm > m) {
                float corr = __expf(m - cm);
                l *= corr;
#pragma unroll
                for (int d = 0; d < 32; d++) acc[d] *= corr;
                m = cm;
            }
#pragma unroll
            for (int j = 0; j < 16; ++j) {
                float p = __expf(s[j] - m);
                l += p;
                const float* vr = &Vs[kk + j][0];
#pragma unroll
                for (int d = 0; d < 32; d += 4) {
                    float4 vv = *(const float4*)(vr + d);
                    acc[d]     += p * vv.x; acc[d + 1] += p * vv.y;
                    acc[d + 2] += p * vv.z; acc[d + 3] += p * vv.w;
                }
            }
        }
        __syncthreads();
    }

    if (act) {
        float inv = 1.f / l;
        float* orow = o + ((long long)n * TLEN + qi) * FEAT + h * HD;
#pragma unroll
        for (int d = 0; d < 32; d += 4) {
            float4 v;
            v.x = acc[d] * inv; v.y = acc[d + 1] * inv;
            v.z = acc[d + 2] * inv; v.w = acc[d + 3] * inv;
            *(float4*)(orow + d) = v;
        }
    }
}

// ---------------------------------------------------------------------------
// LayerNorm over last dim (256), one wave per valid token row.
// ---------------------------------------------------------------------------
__global__ __launch_bounds__(64) void ln_kernel(
    const float* __restrict__ tmp, float* __restrict__ x,
    const float* __restrict__ g, const float* __restrict__ b,
    const int* __restrict__ seqlen)
{
    int t = blockIdx.x, n = blockIdx.y;
    int len = (n & 1) ? 1 : seqlen[n >> 1];
    if (t >= len) return;
    int tid = threadIdx.x;
    const float* row = tmp + ((long long)n * TLEN + t) * FEAT;
    int f = tid * 4;
    float4 v = *(const float4*)(row + f);
    float s = v.x + v.y + v.z + v.w;
#pragma unroll
    for (int off = 32; off; off >>= 1) s += __shfl_down(s, off);
    float mu = __shfl(s, 0) * (1.f / 256.f);
    float dx = v.x - mu, dy = v.y - mu, dz = v.z - mu, dw = v.w - mu;
    float q = dx * dx + dy * dy + dz * dz + dw * dw;
#pragma unroll
    for (int off = 32; off; off >>= 1) q += __shfl_down(q, off);
    float var = __shfl(q, 0) * (1.f / 256.f);
    float r = rsqrtf(var + 1e-5f);
    float4 ov;
    ov.x = dx * r * g[f + 0] + b[f + 0];
    ov.y = dy * r * g[f + 1] + b[f + 1];
    ov.z = dz * r * g[f + 2] + b[f + 2];
    ov.w = dw * r * g[f + 3] + b[f + 3];
    *(float4*)(x + ((long long)n * TLEN + t) * FEAT + f) = ov;
}

// ---------------------------------------------------------------------------
// Masked mean-pool over valid tokens + output projection (written twice:
// shared_ft and shared_gft are identical).
// valid_cxr arrives as int32 (harness maps integer-kind numpy, incl. bool,
// to const int*).
// ---------------------------------------------------------------------------
__global__ __launch_bounds__(256) void pool_out_kernel(
    const float* __restrict__ x, const float* __restrict__ W,
    const float* __restrict__ b, const int* __restrict__ seqlen,
    const int* __restrict__ valid_cxr, float* __restrict__ out)
{
    int n = blockIdx.x;
    int f = threadIdx.x;
    int cnt = (n & 1) ? (valid_cxr[n >> 1] != 0 ? 1 : 0) : seqlen[n >> 1];
    __shared__ float pooled[FEAT];
    float ssum = 0.f;
    const float* xb = x + (long long)n * TLEN * FEAT + f;
    for (int t = 0; t < cnt; ++t) ssum += xb[(long long)t * FEAT];
    pooled[f] = cnt ? ssum / (float)cnt : 0.f;
    __syncthreads();
    float acc = 0.f;
#pragma unroll 4
    for (int k = 0; k < FEAT; ++k) acc += pooled[k] * W[(long long)k * FEAT + f];
    float v = acc + b[f];
    out[(long long)n * FEAT + f] = v;
    out[NROWS * FEAT + (long long)n * FEAT + f] = v;
}

// ---------------------------------------------------------------------------
extern "C" void kernel_launch(void* const* d_in, const int* in_sizes, int n_in,
                              void* d_out, int out_size, void* d_ws, size_t ws_size,
                              hipStream_t stream)
{
    const float* ehr_data = (const float*)d_in[0];
    const float* cxr_data = (const float*)d_in[1];
    const int*   seqlen   = (const int*)d_in[2];
    const int*   valid_cxr = (const int*)d_in[3];
    const float* ehr_w = (const float*)d_in[4];
    const float* ehr_b = (const float*)d_in[5];
    const float* cxr_w = (const float*)d_in[6];
    const float* cxr_b = (const float*)d_in[7];
    const float* modemb = (const float*)d_in[8];
    const float* pos    = (const float*)d_in[9];
    const float* qkv_w  = (const float*)d_in[10];
    const float* qkv_b  = (const float*)d_in[11];
    const float* aow    = (const float*)d_in[12];
    const float* aob    = (const float*)d_in[13];
    const float* ln1g   = (const float*)d_in[14];
    const float* ln1b   = (const float*)d_in[15];
    const float* ln2g   = (const float*)d_in[16];
    const float* ln2b   = (const float*)d_in[17];
    const float* ff1w   = (const float*)d_in[18];
    const float* ff1b   = (const float*)d_in[19];
    const float* ff2w   = (const float*)d_in[20];
    const float* ff2b   = (const float*)d_in[21];
    const float* outw   = (const float*)d_in[22];
    const float* outb   = (const float*)d_in[23];
    float* out = (float*)d_out;

    float* ws   = (float*)d_ws;
    float* x    = ws;                  // 32*501*256  = 4,104,192 floats
    float* qkv  = ws + 4104192;        // 32*501*768  = 12,312,576 floats
    float* obuf = ws + 16416768;       // 32*501*256
    float* tmp  = ws + 20520960;       // 32*501*256   (end: 24,625,152 floats = 98.5 MB)
    float* h    = qkv;                 // 32*501*1024 overlays qkv+obuf (both dead at ff1)

    // ehr projection -> even rows of x
    gemm_frag<<<dim3(8, 4, 16), 256, 0, stream>>>(
        ehr_data, EHR_IN, (long long)MAXLEN * EHR_IN, MAXLEN,
        ehr_w, FEAT, EHR_IN,
        x, FEAT, (long long)2 * TLEN * FEAT,
        ehr_b, nullptr, 0, modemb /*row0*/, pos, seqlen, 0, F_POSEMB);
    // cxr projection -> odd rows token 0
    cxr_proj<<<16, 256, 0, stream>>>(cxr_data, cxr_w, cxr_b, modemb + FEAT, pos, x);

    for (int l = 0; l < NLAYERS; ++l) {
        gemm_frag<<<dim3(8, 12, 32), 256, 0, stream>>>(
            x, FEAT, (long long)TLEN * FEAT, TLEN,
            qkv_w + (long long)l * FEAT * 3 * FEAT, 3 * FEAT, FEAT,
            qkv, 3 * FEAT, (long long)TLEN * 3 * FEAT,
            qkv_b + (long long)l * 3 * FEAT, nullptr, 0, nullptr, nullptr, seqlen, 1, 0);

        attn_kernel<<<dim3(4, NHEAD, NROWS), 128, 0, stream>>>(qkv, obuf, seqlen);

        gemm_frag<<<dim3(8, 4, 32), 256, 0, stream>>>(
            obuf, FEAT, (long long)TLEN * FEAT, TLEN,
            aow + (long long)l * FEAT * FEAT, FEAT, FEAT,
            tmp, FEAT, (long long)TLEN * FEAT,
            aob + (long long)l * FEAT, x, (long long)TLEN * FEAT, nullptr, nullptr, seqlen, 1, F_RESID);

        ln_kernel<<<dim3(TLEN, NROWS), 64, 0, stream>>>(
            tmp, x, ln1g + l * FEAT, ln1b + l * FEAT, seqlen);

        gemm_frag<<<dim3(8, 16, 32), 256, 0, stream>>>(
            x, FEAT, (long long)TLEN * FEAT, TLEN,
            ff1w + (long long)l * FEAT * FFDIM, FFDIM, FEAT,
            h, FFDIM, (long long)TLEN * FFDIM,
            ff1b + (long long)l * FFDIM, nullptr, 0, nullptr, nullptr, seqlen, 1, F_GELU);

        gemm_frag<<<dim3(8, 4, 32), 256, 0, stream>>>(
            h, FFDIM, (long long)TLEN * FFDIM, TLEN,
            ff2w + (long long)l * FFDIM * FEAT, FEAT, FFDIM,
            tmp, FEAT, (long long)TLEN * FEAT,
            ff2b + (long long)l * FEAT, x, (long long)TLEN * FEAT, nullptr, nullptr, seqlen, 1, F_RESID);

        ln_kernel<<<dim3(TLEN, NROWS), 64, 0, stream>>>(
            tmp, x, ln2g + l * FEAT, ln2b + l * FEAT, seqlen);
    }

    pool_out_kernel<<<NROWS, 256, 0, stream>>>(x, outw, outb, seqlen, valid_cxr, out);
}

// Round 3
// 1538.219 us; speedup vs baseline: 1.1937x; 1.1937x over previous
//
#include <hip/hip_runtime.h>
#include <math.h>

#define FEAT 256
#define NHEAD 8
#define HD 32
#define NLAYERS 3
#define EHR_IN 498
#define MAXLEN 500
#define BATCH 16
#define CXR_IN 2048
#define FFDIM 1024
#define NROWS 32
#define TLEN 501

#define F_GELU 1
#define F_RESID 2
#define F_POSEMB 4

// ---------------------------------------------------------------------------
// Generic 64x64 tiled fp32 GEMM: C[z][m][n] = A[z][m][:K] @ B[:K][n] + epilogue
// Rows are ragged: only m < len(z) are computed/stored.
// lenMode 0: len = seq[z] (ehr projection, z = batch index)
// lenMode 1: len = (z&1) ? 1 : seq[z>>1] (token rows, z = sequence index)
// ---------------------------------------------------------------------------
__global__ __launch_bounds__(256) void gemm_frag(
    const float* __restrict__ A, int lda, long long aStrideZ, int Mrows,
    const float* __restrict__ Bw, int ldb, int K,
    float* __restrict__ C, int ldc, long long cStrideZ,
    const float* __restrict__ bias,
    const float* __restrict__ resid, long long resStrideZ,
    const float* __restrict__ modv, const float* __restrict__ posm,
    const int* __restrict__ seqlen, int lenMode, int flags)
{
    int z = blockIdx.z;
    int len = (lenMode == 0) ? seqlen[z] : ((z & 1) ? 1 : seqlen[z >> 1]);
    int m0 = blockIdx.x * 64;
    if (m0 >= len) return;
    int n0 = blockIdx.y * 64;

    const float* Az = A + (long long)z * aStrideZ;
    float* Cz = C + (long long)z * cStrideZ;

    __shared__ float As[16][68];   // [k][m], row stride 68 floats = 272B (16B aligned)
    __shared__ float Bs[16][68];   // [k][n]

    int tid = threadIdx.x;
    int tx = tid & 15, ty = tid >> 4;

    float acc[4][4];
#pragma unroll
    for (int i = 0; i < 4; i++)
#pragma unroll
        for (int j = 0; j < 4; j++) acc[i][j] = 0.f;

    int arow = m0 + (tid >> 2);     // A-load: row
    int ak   = (tid & 3) * 4;       // A-load: k offset within tile
    int am   = tid >> 2;
    int bk   = tid >> 4;            // B-load: k row within tile
    int bncol = n0 + (tid & 15) * 4;

    int nk = (K + 15) >> 4;
    for (int kt = 0; kt < nk; ++kt) {
        int k0 = kt << 4;
        // ---- stage A (transposed) ----
        float4 av = make_float4(0.f, 0.f, 0.f, 0.f);
        if (arow < Mrows) {
            int kk = k0 + ak;
            const float* p = Az + (long long)arow * lda;
            if (kk + 3 < K) {
                av = *(const float4*)(p + kk);
            } else {
                av.x = (kk + 0 < K) ? p[kk + 0] : 0.f;
                av.y = (kk + 1 < K) ? p[kk + 1] : 0.f;
                av.z = (kk + 2 < K) ? p[kk + 2] : 0.f;
                av.w = (kk + 3 < K) ? p[kk + 3] : 0.f;
            }
        }
        As[ak + 0][am] = av.x;
        As[ak + 1][am] = av.y;
        As[ak + 2][am] = av.z;
        As[ak + 3][am] = av.w;
        // ---- stage B ----
        float4 bv = make_float4(0.f, 0.f, 0.f, 0.f);
        int kb = k0 + bk;
        if (kb < K) bv = *(const float4*)(Bw + (long long)kb * ldb + bncol);
        *(float4*)&Bs[bk][(tid & 15) * 4] = bv;

        __syncthreads();
#pragma unroll
        for (int kk = 0; kk < 16; ++kk) {
            float4 a = *(const float4*)&As[kk][ty * 4];
            float4 b = *(const float4*)&Bs[kk][tx * 4];
            acc[0][0] += a.x * b.x; acc[0][1] += a.x * b.y; acc[0][2] += a.x * b.z; acc[0][3] += a.x * b.w;
            acc[1][0] += a.y * b.x; acc[1][1] += a.y * b.y; acc[1][2] += a.y * b.z; acc[1][3] += a.y * b.w;
            acc[2][0] += a.z * b.x; acc[2][1] += a.z * b.y; acc[2][2] += a.z * b.z; acc[2][3] += a.z * b.w;
            acc[3][0] += a.w * b.x; acc[3][1] += a.w * b.y; acc[3][2] += a.w * b.z; acc[3][3] += a.w * b.w;
        }
        __syncthreads();
    }

#pragma unroll
    for (int i = 0; i < 4; i++) {
        int gm = m0 + ty * 4 + i;
        if (gm >= len) continue;
#pragma unroll
        for (int j = 0; j < 4; j++) {
            int gn = n0 + tx * 4 + j;
            float v = acc[i][j] + bias[gn];
            if (flags & F_POSEMB) v += modv[gn] + posm[(long long)gm * FEAT + gn];
            if (flags & F_RESID)  v += resid[(long long)z * resStrideZ + (long long)gm * ldc + gn];
            if (flags & F_GELU)   v = 0.5f * v * (1.f + erff(v * 0.70710678118654752f));
            Cz[(long long)gm * ldc + gn] = v;
        }
    }
}

// ---------------------------------------------------------------------------
// CXR projection: x[2b+1][0][:] = cxr[b] @ cxr_w + cxr_b + mod[1] + pos[0]
// ---------------------------------------------------------------------------
__global__ __launch_bounds__(256) void cxr_proj(
    const float* __restrict__ cxr, const float* __restrict__ W,
    const float* __restrict__ b, const float* __restrict__ mod1,
    const float* __restrict__ pos0, float* __restrict__ x)
{
    int bb = blockIdx.x;
    int j = threadIdx.x;
    const float* xrow = cxr + (long long)bb * CXR_IN;
    float acc = 0.f;
#pragma unroll 8
    for (int k = 0; k < CXR_IN; ++k) acc += xrow[k] * W[(long long)k * FEAT + j];
    float v = acc + b[j] + mod1[j] + pos0[j];
    x[((long long)(2 * bb + 1) * TLEN) * FEAT + j] = v;
}

// ---------------------------------------------------------------------------
// Flash attention, 8-lanes-per-query layout:
//   block = 256 threads = 32 queries x 8 lanes; grid = (qtile, head, seq).
//   64-key K/V tiles staged in LDS (rows padded to 36 floats: read bank =
//   (4g+4c)%32, distinct per lane-group -> conflict-free broadcast).
//   Lane g owns keys g, g+8, ... (online softmax per lane, tile-level
//   rescale); final width-8 shuffle butterfly does exact flash-combine of
//   (m, l, acc[32]). Invalid keys skipped (== -1e9 mask, exp underflow).
// ---------------------------------------------------------------------------
__global__ __launch_bounds__(256) void attn_kernel(
    const float* __restrict__ qkv, float* __restrict__ o,
    const int* __restrict__ seqlen)
{
    int n = blockIdx.z, h = blockIdx.y, qt = blockIdx.x;
    int len = (n & 1) ? 1 : seqlen[n >> 1];
    int q0 = qt * 32;
    if (q0 >= len) return;
    int tid = threadIdx.x;
    int qloc = tid >> 3;
    int g = tid & 7;
    int qi = q0 + qloc;
    bool act = qi < len;

    const float* base = qkv + (long long)n * TLEN * 768;
    const float* qrow = base + (long long)(act ? qi : q0) * 768 + h * HD;
    float qreg[32];
#pragma unroll
    for (int d = 0; d < 32; d += 4) {
        float4 v = *(const float4*)(qrow + d);
        qreg[d] = v.x; qreg[d + 1] = v.y; qreg[d + 2] = v.z; qreg[d + 3] = v.w;
    }

    const float scale = 0.17677669529663687f; // 1/sqrt(32)
    float m = -1e30f, l = 0.f;
    float acc[32];
#pragma unroll
    for (int d = 0; d < 32; d++) acc[d] = 0.f;

    __shared__ float Ks[64][36];
    __shared__ float Vs[64][36];

    for (int k0 = 0; k0 < len; k0 += 64) {
        int kend = min(64, len - k0);
        // ---- stage K/V tile: 64 rows x 8 float4 chunks, 2 chunks/thread ----
        __syncthreads();
#pragma unroll
        for (int i = 0; i < 2; ++i) {
            int idx = tid + i * 256;
            int row = idx >> 3, c = (idx & 7) * 4;
            if (row < kend) {
                const float* kr = base + (long long)(k0 + row) * 768 + 256 + h * HD;
                *(float4*)&Ks[row][c] = *(const float4*)(kr + c);
                *(float4*)&Vs[row][c] = *(const float4*)(kr + 256 + c);
            }
        }
        __syncthreads();

        // ---- scores for this lane's keys ----
        float s[8];
        float tm = -1e30f;
#pragma unroll
        for (int j = 0; j < 8; ++j) {
            int key = g + 8 * j;
            float d0 = 0.f;
            if (key < kend) {
                const float* kr = &Ks[key][0];
#pragma unroll
                for (int d = 0; d < 32; d += 4) {
                    float4 kv = *(const float4*)(kr + d);
                    d0 += qreg[d] * kv.x + qreg[d + 1] * kv.y
                        + qreg[d + 2] * kv.z + qreg[d + 3] * kv.w;
                }
                s[j] = d0 * scale;
                tm = fmaxf(tm, s[j]);
            } else {
                s[j] = -1e30f;
            }
        }
        // ---- tile-level rescale ----
        if (tm > m) {
            float corr = __expf(m - tm);   // 0 when m == -1e30 (acc,l are 0)
            l *= corr;
#pragma unroll
            for (int d = 0; d < 32; d++) acc[d] *= corr;
            m = tm;
        }
        // ---- accumulate PV ----
#pragma unroll
        for (int j = 0; j < 8; ++j) {
            int key = g + 8 * j;
            if (key < kend) {
                float p = __expf(s[j] - m);
                l += p;
                const float* vr = &Vs[key][0];
#pragma unroll
                for (int d = 0; d < 32; d += 4) {
                    float4 vv = *(const float4*)(vr + d);
                    acc[d]     += p * vv.x; acc[d + 1] += p * vv.y;
                    acc[d + 2] += p * vv.z; acc[d + 3] += p * vv.w;
                }
            }
        }
    }

    // ---- width-8 butterfly combine of (m, l, acc[32]) ----
#pragma unroll
    for (int off = 1; off < 8; off <<= 1) {
        float mo = __shfl_xor(m, off);
        float lo = __shfl_xor(l, off);
        float mn = fmaxf(m, mo);
        float fs = __expf(m - mn);
        float fo = __expf(mo - mn);
        l = l * fs + lo * fo;
#pragma unroll
        for (int d = 0; d < 32; d++) {
            float ao = __shfl_xor(acc[d], off);
            acc[d] = acc[d] * fs + ao * fo;
        }
        m = mn;
    }

    if (act) {
        float inv = 1.f / l;
        float* orow = o + ((long long)n * TLEN + qi) * FEAT + h * HD;
#pragma unroll
        for (int d0 = 0; d0 < 8; ++d0) {
            if (g == d0) {
                float4 v;
                v.x = acc[4 * d0 + 0] * inv; v.y = acc[4 * d0 + 1] * inv;
                v.z = acc[4 * d0 + 2] * inv; v.w = acc[4 * d0 + 3] * inv;
                *(float4*)(orow + 4 * d0) = v;
            }
        }
    }
}

// ---------------------------------------------------------------------------
// LayerNorm over last dim (256), one wave per valid token row.
// ---------------------------------------------------------------------------
__global__ __launch_bounds__(64) void ln_kernel(
    const float* __restrict__ tmp, float* __restrict__ x,
    const float* __restrict__ g, const float* __restrict__ b,
    const int* __restrict__ seqlen)
{
    int t = blockIdx.x, n = blockIdx.y;
    int len = (n & 1) ? 1 : seqlen[n >> 1];
    if (t >= len) return;
    int tid = threadIdx.x;
    const float* row = tmp + ((long long)n * TLEN + t) * FEAT;
    int f = tid * 4;
    float4 v = *(const float4*)(row + f);
    float s = v.x + v.y + v.z + v.w;
#pragma unroll
    for (int off = 32; off; off >>= 1) s += __shfl_down(s, off);
    float mu = __shfl(s, 0) * (1.f / 256.f);
    float dx = v.x - mu, dy = v.y - mu, dz = v.z - mu, dw = v.w - mu;
    float q = dx * dx + dy * dy + dz * dz + dw * dw;
#pragma unroll
    for (int off = 32; off; off >>= 1) q += __shfl_down(q, off);
    float var = __shfl(q, 0) * (1.f / 256.f);
    float r = rsqrtf(var + 1e-5f);
    float4 ov;
    ov.x = dx * r * g[f + 0] + b[f + 0];
    ov.y = dy * r * g[f + 1] + b[f + 1];
    ov.z = dz * r * g[f + 2] + b[f + 2];
    ov.w = dw * r * g[f + 3] + b[f + 3];
    *(float4*)(x + ((long long)n * TLEN + t) * FEAT + f) = ov;
}

// ---------------------------------------------------------------------------
// Masked mean-pool over valid tokens + output projection (written twice:
// shared_ft and shared_gft are identical). valid_cxr arrives as int32.
// ---------------------------------------------------------------------------
__global__ __launch_bounds__(256) void pool_out_kernel(
    const float* __restrict__ x, const float* __restrict__ W,
    const float* __restrict__ b, const int* __restrict__ seqlen,
    const int* __restrict__ valid_cxr, float* __restrict__ out)
{
    int n = blockIdx.x;
    int f = threadIdx.x;
    int cnt = (n & 1) ? (valid_cxr[n >> 1] != 0 ? 1 : 0) : seqlen[n >> 1];
    __shared__ float pooled[FEAT];
    float ssum = 0.f;
    const float* xb = x + (long long)n * TLEN * FEAT + f;
    for (int t = 0; t < cnt; ++t) ssum += xb[(long long)t * FEAT];
    pooled[f] = cnt ? ssum / (float)cnt : 0.f;
    __syncthreads();
    float acc = 0.f;
#pragma unroll 4
    for (int k = 0; k < FEAT; ++k) acc += pooled[k] * W[(long long)k * FEAT + f];
    float v = acc + b[f];
    out[(long long)n * FEAT + f] = v;
    out[NROWS * FEAT + (long long)n * FEAT + f] = v;
}

// ---------------------------------------------------------------------------
extern "C" void kernel_launch(void* const* d_in, const int* in_sizes, int n_in,
                              void* d_out, int out_size, void* d_ws, size_t ws_size,
                              hipStream_t stream)
{
    const float* ehr_data = (const float*)d_in[0];
    const float* cxr_data = (const float*)d_in[1];
    const int*   seqlen   = (const int*)d_in[2];
    const int*   valid_cxr = (const int*)d_in[3];
    const float* ehr_w = (const float*)d_in[4];
    const float* ehr_b = (const float*)d_in[5];
    const float* cxr_w = (const float*)d_in[6];
    const float* cxr_b = (const float*)d_in[7];
    const float* modemb = (const float*)d_in[8];
    const float* pos    = (const float*)d_in[9];
    const float* qkv_w  = (const float*)d_in[10];
    const float* qkv_b  = (const float*)d_in[11];
    const float* aow    = (const float*)d_in[12];
    const float* aob    = (const float*)d_in[13];
    const float* ln1g   = (const float*)d_in[14];
    const float* ln1b   = (const float*)d_in[15];
    const float* ln2g   = (const float*)d_in[16];
    const float* ln2b   = (const float*)d_in[17];
    const float* ff1w   = (const float*)d_in[18];
    const float* ff1b   = (const float*)d_in[19];
    const float* ff2w   = (const float*)d_in[20];
    const float* ff2b   = (const float*)d_in[21];
    const float* outw   = (const float*)d_in[22];
    const float* outb   = (const float*)d_in[23];
    float* out = (float*)d_out;

    float* ws   = (float*)d_ws;
    float* x    = ws;                  // 32*501*256  = 4,104,192 floats
    float* qkv  = ws + 4104192;        // 32*501*768  = 12,312,576 floats
    float* obuf = ws + 16416768;       // 32*501*256
    float* tmp  = ws + 20520960;       // 32*501*256   (end: 24,625,152 floats = 98.5 MB)
    float* h    = qkv;                 // 32*501*1024 overlays qkv+obuf (both dead at ff1)

    // ehr projection -> even rows of x
    gemm_frag<<<dim3(8, 4, 16), 256, 0, stream>>>(
        ehr_data, EHR_IN, (long long)MAXLEN * EHR_IN, MAXLEN,
        ehr_w, FEAT, EHR_IN,
        x, FEAT, (long long)2 * TLEN * FEAT,
        ehr_b, nullptr, 0, modemb /*row0*/, pos, seqlen, 0, F_POSEMB);
    // cxr projection -> odd rows token 0
    cxr_proj<<<16, 256, 0, stream>>>(cxr_data, cxr_w, cxr_b, modemb + FEAT, pos, x);

    for (int l = 0; l < NLAYERS; ++l) {
        gemm_frag<<<dim3(8, 12, 32), 256, 0, stream>>>(
            x, FEAT, (long long)TLEN * FEAT, TLEN,
            qkv_w + (long long)l * FEAT * 3 * FEAT, 3 * FEAT, FEAT,
            qkv, 3 * FEAT, (long long)TLEN * 3 * FEAT,
            qkv_b + (long long)l * 3 * FEAT, nullptr, 0, nullptr, nullptr, seqlen, 1, 0);

        attn_kernel<<<dim3(16, NHEAD, NROWS), 256, 0, stream>>>(qkv, obuf, seqlen);

        gemm_frag<<<dim3(8, 4, 32), 256, 0, stream>>>(
            obuf, FEAT, (long long)TLEN * FEAT, TLEN,
            aow + (long long)l * FEAT * FEAT, FEAT, FEAT,
            tmp, FEAT, (long long)TLEN * FEAT,
            aob + (long long)l * FEAT, x, (long long)TLEN * FEAT, nullptr, nullptr, seqlen, 1, F_RESID);

        ln_kernel<<<dim3(TLEN, NROWS), 64, 0, stream>>>(
            tmp, x, ln1g + l * FEAT, ln1b + l * FEAT, seqlen);

        gemm_frag<<<dim3(8, 16, 32), 256, 0, stream>>>(
            x, FEAT, (long long)TLEN * FEAT, TLEN,
            ff1w + (long long)l * FEAT * FFDIM, FFDIM, FEAT,
            h, FFDIM, (long long)TLEN * FFDIM,
            ff1b + (long long)l * FFDIM, nullptr, 0, nullptr, nullptr, seqlen, 1, F_GELU);

        gemm_frag<<<dim3(8, 4, 32), 256, 0, stream>>>(
            h, FFDIM, (long long)TLEN * FFDIM, TLEN,
            ff2w + (long long)l * FFDIM * FEAT, FEAT, FFDIM,
            tmp, FEAT, (long long)TLEN * FEAT,
            ff2b + (long long)l * FEAT, x, (long long)TLEN * FEAT, nullptr, nullptr, seqlen, 1, F_RESID);

        ln_kernel<<<dim3(TLEN, NROWS), 64, 0, stream>>>(
            tmp, x, ln2g + l * FEAT, ln2b + l * FEAT, seqlen);
    }

    pool_out_kernel<<<NROWS, 256, 0, stream>>>(x, outw, outb, seqlen, valid_cxr, out);
}

// Round 4
// 862.979 us; speedup vs baseline: 2.1277x; 1.7825x over previous
//
#include <hip/hip_runtime.h>
#include <math.h>

#define FEAT 256
#define NHEAD 8
#define HD 32
#define NLAYERS 3
#define EHR_IN 498
#define MAXLEN 500
#define BATCH 16
#define CXR_IN 2048
#define FFDIM 1024
#define NROWS 32
#define TLEN 501

#define F_GELU 1
#define F_RESID 2
#define F_POSEMB 4

typedef __bf16 bf16x8 __attribute__((ext_vector_type(8)));
typedef __bf16 bf16x4 __attribute__((ext_vector_type(4)));
typedef float f32x4 __attribute__((ext_vector_type(4)));

// ---------------------------------------------------------------------------
// Weight prep: fp32 W[K][N] -> bf16 W^T[N][Kpad] (zero-padded K), all
// matrices in one dispatch. 32x32 tiles via LDS.
// ---------------------------------------------------------------------------
struct WDesc { const float* src; unsigned dstOff; int K, N, Kpad; };
struct WPack { WDesc d[13]; };

__global__ __launch_bounds__(256) void wconv_kernel(WPack p, __bf16* __restrict__ wb)
{
    WDesc w = p.d[blockIdx.z];
    int n0 = blockIdx.x * 32, k0 = blockIdx.y * 32;
    if (n0 >= w.N || k0 >= w.Kpad) return;
    __shared__ float t[32][33];
    int tid = threadIdx.x;
    int c = tid & 31, r = tid >> 5;           // load: col n, 8 k-rows/thread
#pragma unroll
    for (int i = 0; i < 4; ++i) {
        int k = k0 + r + i * 8;
        int n = n0 + c;
        t[r + i * 8][c] = (k < w.K && n < w.N) ? w.src[(long long)k * w.N + n] : 0.f;
    }
    __syncthreads();
    int nl = tid >> 3, kq = (tid & 7) * 4;    // write: 4 bf16 along k
    int n = n0 + nl;
    if (n < w.N) {
        bf16x4 v;
#pragma unroll
        for (int j = 0; j < 4; ++j) v[j] = (__bf16)t[kq + j][nl];
        *(bf16x4*)(wb + w.dstOff + (long long)n * w.Kpad + k0 + kq) = v;
    }
}

// ---------------------------------------------------------------------------
// bf16 MFMA GEMM: C[z][m][n] = A[z][m][:K] @ W  (+ epilogue), W given as
// bf16 W^T[N][Kpad]. Tile 64x64, BK=32, 4 waves of 2x2 16x16x32 fragments.
// A is fp32, converted to bf16 while staging. Ragged rows as before.
// Fragment layouts (m89-verified family):
//   A: m=lane&15, k=(lane>>4)*8+j ; B: n=lane&15, same k
//   C/D: col=lane&15, row=(lane>>4)*4+reg
// LDS rows padded to 40 bf16 (80 B): worst aliasing 2-way (free).
// ---------------------------------------------------------------------------
__global__ __launch_bounds__(256) void gemm_mfma(
    const float* __restrict__ A, int lda, long long aStrideZ, int Mrows,
    const __bf16* __restrict__ WT, int kpad, int K,
    float* __restrict__ C, int ldc, long long cStrideZ,
    const float* __restrict__ bias,
    const float* __restrict__ resid, long long resStrideZ,
    const float* __restrict__ modv, const float* __restrict__ posm,
    const int* __restrict__ seqlen, int lenMode, int flags)
{
    int z = blockIdx.z;
    int len = (lenMode == 0) ? seqlen[z] : ((z & 1) ? 1 : seqlen[z >> 1]);
    int m0 = blockIdx.x * 64;
    if (m0 >= len) return;
    int n0 = blockIdx.y * 64;

    const float* Az = A + (long long)z * aStrideZ;
    float* Cz = C + (long long)z * cStrideZ;

    __shared__ __bf16 As[64][40];
    __shared__ __bf16 Bs[64][40];

    int tid = threadIdx.x;
    int wave = tid >> 6, lane = tid & 63;
    int wm = wave >> 1, wn = wave & 1;
    int fm = lane & 15, kgrp = lane >> 4;

    f32x4 acc[2][2];
#pragma unroll
    for (int i = 0; i < 2; ++i)
#pragma unroll
        for (int j = 0; j < 2; ++j)
#pragma unroll
            for (int r = 0; r < 4; ++r) acc[i][j][r] = 0.f;

    int srow = tid >> 2;          // staging row 0..63
    int skq  = (tid & 3) * 8;     // k offset 0/8/16/24
    int garow = m0 + srow;
    bool rowok = garow < Mrows;
    bool a16 = ((lda & 3) == 0);  // uniform: float4-able A rows

    int nk = (K + 31) >> 5;
    for (int kt = 0; kt < nk; ++kt) {
        int k0 = kt << 5;
        // ---- stage A (fp32 -> bf16) ----
        float va[8];
        const float* ap = Az + (long long)garow * lda + k0 + skq;
        if (rowok && a16 && k0 + skq + 7 < K) {
            float4 t0 = *(const float4*)(ap);
            float4 t1 = *(const float4*)(ap + 4);
            va[0] = t0.x; va[1] = t0.y; va[2] = t0.z; va[3] = t0.w;
            va[4] = t1.x; va[5] = t1.y; va[6] = t1.z; va[7] = t1.w;
        } else if (rowok && !a16 && k0 + skq + 7 < K) {
            // 8-byte aligned path (lda even, e.g. 498)
#pragma unroll
            for (int j = 0; j < 8; j += 2) {
                float2 t = *(const float2*)(ap + j);
                va[j] = t.x; va[j + 1] = t.y;
            }
        } else {
#pragma unroll
            for (int j = 0; j < 8; ++j)
                va[j] = (rowok && k0 + skq + j < K) ? ap[j] : 0.f;
        }
        bf16x8 ab;
#pragma unroll
        for (int j = 0; j < 8; ++j) ab[j] = (__bf16)va[j];
        *(bf16x8*)&As[srow][skq] = ab;
        // ---- stage B (bf16 W^T) ----
        bf16x8 bb = *(const bf16x8*)(WT + (long long)(n0 + srow) * kpad + k0 + skq);
        *(bf16x8*)&Bs[srow][skq] = bb;

        __syncthreads();
        bf16x8 bfr[2];
#pragma unroll
        for (int j = 0; j < 2; ++j)
            bfr[j] = *(const bf16x8*)&Bs[wn * 32 + j * 16 + fm][kgrp * 8];
#pragma unroll
        for (int i = 0; i < 2; ++i) {
            bf16x8 af = *(const bf16x8*)&As[wm * 32 + i * 16 + fm][kgrp * 8];
#pragma unroll
            for (int j = 0; j < 2; ++j)
                acc[i][j] = __builtin_amdgcn_mfma_f32_16x16x32_bf16(af, bfr[j], acc[i][j], 0, 0, 0);
        }
        __syncthreads();
    }

    // ---- epilogue ----
    int rbase = (lane >> 4) * 4;
    int ccol = lane & 15;
#pragma unroll
    for (int i = 0; i < 2; ++i) {
#pragma unroll
        for (int r = 0; r < 4; ++r) {
            int gm = m0 + wm * 32 + i * 16 + rbase + r;
            if (gm >= len) continue;
#pragma unroll
            for (int j = 0; j < 2; ++j) {
                int gn = n0 + wn * 32 + j * 16 + ccol;
                float v = acc[i][j][r] + bias[gn];
                if (flags & F_POSEMB) v += modv[gn] + posm[(long long)gm * FEAT + gn];
                if (flags & F_RESID)  v += resid[(long long)z * resStrideZ + (long long)gm * ldc + gn];
                if (flags & F_GELU)   v = 0.5f * v * (1.f + erff(v * 0.70710678118654752f));
                Cz[(long long)gm * ldc + gn] = v;
            }
        }
    }
}

// ---------------------------------------------------------------------------
// CXR projection: x[2b+1][0][:] = cxr[b] @ cxr_w + cxr_b + mod[1] + pos[0]
// ---------------------------------------------------------------------------
__global__ __launch_bounds__(256) void cxr_proj(
    const float* __restrict__ cxr, const float* __restrict__ W,
    const float* __restrict__ b, const float* __restrict__ mod1,
    const float* __restrict__ pos0, float* __restrict__ x)
{
    int bb = blockIdx.x;
    int j = threadIdx.x;
    const float* xrow = cxr + (long long)bb * CXR_IN;
    float acc = 0.f;
#pragma unroll 8
    for (int k = 0; k < CXR_IN; ++k) acc += xrow[k] * W[(long long)k * FEAT + j];
    float v = acc + b[j] + mod1[j] + pos0[j];
    x[((long long)(2 * bb + 1) * TLEN) * FEAT + j] = v;
}

// ---------------------------------------------------------------------------
// Flash attention, 8-lanes-per-query (round-3 version, fp32).
// ---------------------------------------------------------------------------
__global__ __launch_bounds__(256) void attn_kernel(
    const float* __restrict__ qkv, float* __restrict__ o,
    const int* __restrict__ seqlen)
{
    int n = blockIdx.z, h = blockIdx.y, qt = blockIdx.x;
    int len = (n & 1) ? 1 : seqlen[n >> 1];
    int q0 = qt * 32;
    if (q0 >= len) return;
    int tid = threadIdx.x;
    int qloc = tid >> 3;
    int g = tid & 7;
    int qi = q0 + qloc;
    bool act = qi < len;

    const float* base = qkv + (long long)n * TLEN * 768;
    const float* qrow = base + (long long)(act ? qi : q0) * 768 + h * HD;
    float qreg[32];
#pragma unroll
    for (int d = 0; d < 32; d += 4) {
        float4 v = *(const float4*)(qrow + d);
        qreg[d] = v.x; qreg[d + 1] = v.y; qreg[d + 2] = v.z; qreg[d + 3] = v.w;
    }

    const float scale = 0.17677669529663687f; // 1/sqrt(32)
    float m = -1e30f, l = 0.f;
    float acc[32];
#pragma unroll
    for (int d = 0; d < 32; d++) acc[d] = 0.f;

    __shared__ float Ks[64][36];
    __shared__ float Vs[64][36];

    for (int k0 = 0; k0 < len; k0 += 64) {
        int kend = min(64, len - k0);
        __syncthreads();
#pragma unroll
        for (int i = 0; i < 2; ++i) {
            int idx = tid + i * 256;
            int row = idx >> 3, c = (idx & 7) * 4;
            if (row < kend) {
                const float* kr = base + (long long)(k0 + row) * 768 + 256 + h * HD;
                *(float4*)&Ks[row][c] = *(const float4*)(kr + c);
                *(float4*)&Vs[row][c] = *(const float4*)(kr + 256 + c);
            }
        }
        __syncthreads();

        float s[8];
        float tm = -1e30f;
#pragma unroll
        for (int j = 0; j < 8; ++j) {
            int key = g + 8 * j;
            float d0 = 0.f;
            if (key < kend) {
                const float* kr = &Ks[key][0];
#pragma unroll
                for (int d = 0; d < 32; d += 4) {
                    float4 kv = *(const float4*)(kr + d);
                    d0 += qreg[d] * kv.x + qreg[d + 1] * kv.y
                        + qreg[d + 2] * kv.z + qreg[d + 3] * kv.w;
                }
                s[j] = d0 * scale;
                tm = fmaxf(tm, s[j]);
            } else {
                s[j] = -1e30f;
            }
        }
        if (tm > m) {
            float corr = __expf(m - tm);
            l *= corr;
#pragma unroll
            for (int d = 0; d < 32; d++) acc[d] *= corr;
            m = tm;
        }
#pragma unroll
        for (int j = 0; j < 8; ++j) {
            int key = g + 8 * j;
            if (key < kend) {
                float p = __expf(s[j] - m);
                l += p;
                const float* vr = &Vs[key][0];
#pragma unroll
                for (int d = 0; d < 32; d += 4) {
                    float4 vv = *(const float4*)(vr + d);
                    acc[d]     += p * vv.x; acc[d + 1] += p * vv.y;
                    acc[d + 2] += p * vv.z; acc[d + 3] += p * vv.w;
                }
            }
        }
    }

#pragma unroll
    for (int off = 1; off < 8; off <<= 1) {
        float mo = __shfl_xor(m, off);
        float lo = __shfl_xor(l, off);
        float mn = fmaxf(m, mo);
        float fs = __expf(m - mn);
        float fo = __expf(mo - mn);
        l = l * fs + lo * fo;
#pragma unroll
        for (int d = 0; d < 32; d++) {
            float ao = __shfl_xor(acc[d], off);
            acc[d] = acc[d] * fs + ao * fo;
        }
        m = mn;
    }

    if (act) {
        float inv = 1.f / l;
        float* orow = o + ((long long)n * TLEN + qi) * FEAT + h * HD;
#pragma unroll
        for (int d0 = 0; d0 < 8; ++d0) {
            if (g == d0) {
                float4 v;
                v.x = acc[4 * d0 + 0] * inv; v.y = acc[4 * d0 + 1] * inv;
                v.z = acc[4 * d0 + 2] * inv; v.w = acc[4 * d0 + 3] * inv;
                *(float4*)(orow + 4 * d0) = v;
            }
        }
    }
}

// ---------------------------------------------------------------------------
// LayerNorm over last dim (256), one wave per valid token row.
// ---------------------------------------------------------------------------
__global__ __launch_bounds__(64) void ln_kernel(
    const float* __restrict__ tmp, float* __restrict__ x,
    const float* __restrict__ g, const float* __restrict__ b,
    const int* __restrict__ seqlen)
{
    int t = blockIdx.x, n = blockIdx.y;
    int len = (n & 1) ? 1 : seqlen[n >> 1];
    if (t >= len) return;
    int tid = threadIdx.x;
    const float* row = tmp + ((long long)n * TLEN + t) * FEAT;
    int f = tid * 4;
    float4 v = *(const float4*)(row + f);
    float s = v.x + v.y + v.z + v.w;
#pragma unroll
    for (int off = 32; off; off >>= 1) s += __shfl_down(s, off);
    float mu = __shfl(s, 0) * (1.f / 256.f);
    float dx = v.x - mu, dy = v.y - mu, dz = v.z - mu, dw = v.w - mu;
    float q = dx * dx + dy * dy + dz * dz + dw * dw;
#pragma unroll
    for (int off = 32; off; off >>= 1) q += __shfl_down(q, off);
    float var = __shfl(q, 0) * (1.f / 256.f);
    float r = rsqrtf(var + 1e-5f);
    float4 ov;
    ov.x = dx * r * g[f + 0] + b[f + 0];
    ov.y = dy * r * g[f + 1] + b[f + 1];
    ov.z = dz * r * g[f + 2] + b[f + 2];
    ov.w = dw * r * g[f + 3] + b[f + 3];
    *(float4*)(x + ((long long)n * TLEN + t) * FEAT + f) = ov;
}

// ---------------------------------------------------------------------------
// Masked mean-pool + output projection (x2 outputs). valid_cxr is int32.
// ---------------------------------------------------------------------------
__global__ __launch_bounds__(256) void pool_out_kernel(
    const float* __restrict__ x, const float* __restrict__ W,
    const float* __restrict__ b, const int* __restrict__ seqlen,
    const int* __restrict__ valid_cxr, float* __restrict__ out)
{
    int n = blockIdx.x;
    int f = threadIdx.x;
    int cnt = (n & 1) ? (valid_cxr[n >> 1] != 0 ? 1 : 0) : seqlen[n >> 1];
    __shared__ float pooled[FEAT];
    float ssum = 0.f;
    const float* xb = x + (long long)n * TLEN * FEAT + f;
    for (int t = 0; t < cnt; ++t) ssum += xb[(long long)t * FEAT];
    pooled[f] = cnt ? ssum / (float)cnt : 0.f;
    __syncthreads();
    float acc = 0.f;
#pragma unroll 4
    for (int k = 0; k < FEAT; ++k) acc += pooled[k] * W[(long long)k * FEAT + f];
    float v = acc + b[f];
    out[(long long)n * FEAT + f] = v;
    out[NROWS * FEAT + (long long)n * FEAT + f] = v;
}

// ---------------------------------------------------------------------------
extern "C" void kernel_launch(void* const* d_in, const int* in_sizes, int n_in,
                              void* d_out, int out_size, void* d_ws, size_t ws_size,
                              hipStream_t stream)
{
    const float* ehr_data = (const float*)d_in[0];
    const float* cxr_data = (const float*)d_in[1];
    const int*   seqlen   = (const int*)d_in[2];
    const int*   valid_cxr = (const int*)d_in[3];
    const float* ehr_w = (const float*)d_in[4];
    const float* ehr_b = (const float*)d_in[5];
    const float* cxr_w = (const float*)d_in[6];
    const float* cxr_b = (const float*)d_in[7];
    const float* modemb = (const float*)d_in[8];
    const float* pos    = (const float*)d_in[9];
    const float* qkv_w  = (const float*)d_in[10];
    const float* qkv_b  = (const float*)d_in[11];
    const float* aow    = (const float*)d_in[12];
    const float* aob    = (const float*)d_in[13];
    const float* ln1g   = (const float*)d_in[14];
    const float* ln1b   = (const float*)d_in[15];
    const float* ln2g   = (const float*)d_in[16];
    const float* ln2b   = (const float*)d_in[17];
    const float* ff1w   = (const float*)d_in[18];
    const float* ff1b   = (const float*)d_in[19];
    const float* ff2w   = (const float*)d_in[20];
    const float* ff2b   = (const float*)d_in[21];
    const float* outw   = (const float*)d_in[22];
    const float* outb   = (const float*)d_in[23];
    float* out = (float*)d_out;

    float* ws   = (float*)d_ws;
    float* x    = ws;                  // 32*501*256  = 4,104,192 floats
    float* qkv  = ws + 4104192;        // 32*501*768  = 12,312,576 floats
    float* obuf = ws + 16416768;       // 32*501*256
    float* tmp  = ws + 20520960;       // 32*501*256
    float* h    = qkv;                 // 32*501*1024 overlays qkv+obuf
    __bf16* wb  = (__bf16*)(ws + 24625152);  // bf16 W^T pool: 2,490,368 elems (~5 MB)

    // ---- weight conversion descriptors (bf16 W^T[N][Kpad]) ----
    WPack p;
    unsigned off = 0;
    // 0: ehr_w [498][256] -> [256][512]
    p.d[0] = { ehr_w, off, EHR_IN, FEAT, 512 };            off += 256 * 512;
    unsigned qkvOff = off;
    for (int l = 0; l < 3; ++l) { p.d[1 + l] = { qkv_w + (long long)l * FEAT * 768, off, FEAT, 768, FEAT };  off += 768 * FEAT; }
    unsigned aoOff = off;
    for (int l = 0; l < 3; ++l) { p.d[4 + l] = { aow + (long long)l * FEAT * FEAT, off, FEAT, FEAT, FEAT };  off += FEAT * FEAT; }
    unsigned ff1Off = off;
    for (int l = 0; l < 3; ++l) { p.d[7 + l] = { ff1w + (long long)l * FEAT * FFDIM, off, FEAT, FFDIM, FEAT }; off += FFDIM * FEAT; }
    unsigned ff2Off = off;
    for (int l = 0; l < 3; ++l) { p.d[10 + l] = { ff2w + (long long)l * FFDIM * FEAT, off, FFDIM, FEAT, FFDIM }; off += FEAT * FFDIM; }

    wconv_kernel<<<dim3(32, 32, 13), 256, 0, stream>>>(p, wb);

    // ehr projection -> even rows of x
    gemm_mfma<<<dim3(8, 4, 16), 256, 0, stream>>>(
        ehr_data, EHR_IN, (long long)MAXLEN * EHR_IN, MAXLEN,
        wb + 0, 512, EHR_IN,
        x, FEAT, (long long)2 * TLEN * FEAT,
        ehr_b, nullptr, 0, modemb /*row0*/, pos, seqlen, 0, F_POSEMB);
    // cxr projection -> odd rows token 0
    cxr_proj<<<16, 256, 0, stream>>>(cxr_data, cxr_w, cxr_b, modemb + FEAT, pos, x);

    for (int l = 0; l < NLAYERS; ++l) {
        gemm_mfma<<<dim3(8, 12, 32), 256, 0, stream>>>(
            x, FEAT, (long long)TLEN * FEAT, TLEN,
            wb + qkvOff + (long long)l * 768 * FEAT, FEAT, FEAT,
            qkv, 3 * FEAT, (long long)TLEN * 3 * FEAT,
            qkv_b + (long long)l * 3 * FEAT, nullptr, 0, nullptr, nullptr, seqlen, 1, 0);

        attn_kernel<<<dim3(16, NHEAD, NROWS), 256, 0, stream>>>(qkv, obuf, seqlen);

        gemm_mfma<<<dim3(8, 4, 32), 256, 0, stream>>>(
            obuf, FEAT, (long long)TLEN * FEAT, TLEN,
            wb + aoOff + (long long)l * FEAT * FEAT, FEAT, FEAT,
            tmp, FEAT, (long long)TLEN * FEAT,
            aob + (long long)l * FEAT, x, (long long)TLEN * FEAT, nullptr, nullptr, seqlen, 1, F_RESID);

        ln_kernel<<<dim3(TLEN, NROWS), 64, 0, stream>>>(
            tmp, x, ln1g + l * FEAT, ln1b + l * FEAT, seqlen);

        gemm_mfma<<<dim3(8, 16, 32), 256, 0, stream>>>(
            x, FEAT, (long long)TLEN * FEAT, TLEN,
            wb + ff1Off + (long long)l * FFDIM * FEAT, FEAT, FEAT,
            h, FFDIM, (long long)TLEN * FFDIM,
            ff1b + (long long)l * FFDIM, nullptr, 0, nullptr, nullptr, seqlen, 1, F_GELU);

        gemm_mfma<<<dim3(8, 4, 32), 256, 0, stream>>>(
            h, FFDIM, (long long)TLEN * FFDIM, TLEN,
            wb + ff2Off + (long long)l * FEAT * FFDIM, FFDIM, FFDIM,
            tmp, FEAT, (long long)TLEN * FEAT,
            ff2b + (long long)l * FEAT, x, (long long)TLEN * FEAT, nullptr, nullptr, seqlen, 1, F_RESID);

        ln_kernel<<<dim3(TLEN, NROWS), 64, 0, stream>>>(
            tmp, x, ln2g + l * FEAT, ln2b + l * FEAT, seqlen);
    }

    pool_out_kernel<<<NROWS, 256, 0, stream>>>(x, outw, outb, seqlen, valid_cxr, out);
}

// Round 5
// 688.892 us; speedup vs baseline: 2.6654x; 1.2527x over previous
//
#include <hip/hip_runtime.h>
#include <math.h>

#define FEAT 256
#define NHEAD 8
#define HD 32
#define NLAYERS 3
#define EHR_IN 498
#define MAXLEN 500
#define BATCH 16
#define CXR_IN 2048
#define FFDIM 1024
#define NROWS 32
#define TLEN 501

#define F_GELU 1
#define F_RESID 2
#define F_POSEMB 4
#define F_POS0 8

typedef __bf16 bf16x8 __attribute__((ext_vector_type(8)));
typedef __bf16 bf16x4 __attribute__((ext_vector_type(4)));
typedef float f32x4 __attribute__((ext_vector_type(4)));

// ---------------------------------------------------------------------------
// Weight prep: fp32 W[K][N] -> bf16 W^T[N][Kpad] (zero-padded K), all
// matrices in one dispatch. 32x32 tiles via LDS.
// ---------------------------------------------------------------------------
struct WDesc { const float* src; unsigned dstOff; int K, N, Kpad; };
struct WPack { WDesc d[14]; };

__global__ __launch_bounds__(256) void wconv_kernel(WPack p, __bf16* __restrict__ wb)
{
    WDesc w = p.d[blockIdx.z];
    int n0 = blockIdx.x * 32, k0 = blockIdx.y * 32;
    if (n0 >= w.N || k0 >= w.Kpad) return;
    __shared__ float t[32][33];
    int tid = threadIdx.x;
    int c = tid & 31, r = tid >> 5;           // load: col n, 8 k-rows/thread
#pragma unroll
    for (int i = 0; i < 4; ++i) {
        int k = k0 + r + i * 8;
        int n = n0 + c;
        t[r + i * 8][c] = (k < w.K && n < w.N) ? w.src[(long long)k * w.N + n] : 0.f;
    }
    __syncthreads();
    int nl = tid >> 3, kq = (tid & 7) * 4;    // write: 4 bf16 along k
    int n = n0 + nl;
    if (n < w.N) {
        bf16x4 v;
#pragma unroll
        for (int j = 0; j < 4; ++j) v[j] = (__bf16)t[kq + j][nl];
        *(bf16x4*)(wb + w.dstOff + (long long)n * w.Kpad + k0 + kq) = v;
    }
}

// ---------------------------------------------------------------------------
// bf16 MFMA GEMM: C[z][m][n] = A[z][m][:K] @ W  (+ epilogue), W given as
// bf16 W^T[N][Kpad]. Tile 64x64, BK=32, 4 waves of 2x2 16x16x32 fragments.
// A is fp32, converted to bf16 while staging. Ragged rows as before.
// Fragment layouts (m89-verified family):
//   A: m=lane&15, k=(lane>>4)*8+j ; B: n=lane&15, same k
//   C/D: col=lane&15, row=(lane>>4)*4+reg
// LDS rows padded to 40 bf16 (80 B): worst aliasing 2-way (free).
// lenMode: 0 = seq[z], 1 = interleaved token rows, 2 = dense (len = Mrows).
// ---------------------------------------------------------------------------
__global__ __launch_bounds__(256) void gemm_mfma(
    const float* __restrict__ A, int lda, long long aStrideZ, int Mrows,
    const __bf16* __restrict__ WT, int kpad, int K,
    float* __restrict__ C, int ldc, long long cStrideZ,
    const float* __restrict__ bias,
    const float* __restrict__ resid, long long resStrideZ,
    const float* __restrict__ modv, const float* __restrict__ posm,
    const int* __restrict__ seqlen, int lenMode, int flags)
{
    int z = blockIdx.z;
    int len = (lenMode == 2) ? Mrows
            : (lenMode == 0) ? seqlen[z]
            : ((z & 1) ? 1 : seqlen[z >> 1]);
    int m0 = blockIdx.x * 64;
    if (m0 >= len) return;
    int n0 = blockIdx.y * 64;

    const float* Az = A + (long long)z * aStrideZ;
    float* Cz = C + (long long)z * cStrideZ;

    __shared__ __bf16 As[64][40];
    __shared__ __bf16 Bs[64][40];

    int tid = threadIdx.x;
    int wave = tid >> 6, lane = tid & 63;
    int wm = wave >> 1, wn = wave & 1;
    int fm = lane & 15, kgrp = lane >> 4;

    f32x4 acc[2][2];
#pragma unroll
    for (int i = 0; i < 2; ++i)
#pragma unroll
        for (int j = 0; j < 2; ++j)
#pragma unroll
            for (int r = 0; r < 4; ++r) acc[i][j][r] = 0.f;

    int srow = tid >> 2;          // staging row 0..63
    int skq  = (tid & 3) * 8;     // k offset 0/8/16/24
    int garow = m0 + srow;
    bool rowok = garow < Mrows;
    bool a16 = ((lda & 3) == 0);  // uniform: float4-able A rows

    int nk = (K + 31) >> 5;
    for (int kt = 0; kt < nk; ++kt) {
        int k0 = kt << 5;
        // ---- stage A (fp32 -> bf16) ----
        float va[8];
        const float* ap = Az + (long long)garow * lda + k0 + skq;
        if (rowok && a16 && k0 + skq + 7 < K) {
            float4 t0 = *(const float4*)(ap);
            float4 t1 = *(const float4*)(ap + 4);
            va[0] = t0.x; va[1] = t0.y; va[2] = t0.z; va[3] = t0.w;
            va[4] = t1.x; va[5] = t1.y; va[6] = t1.z; va[7] = t1.w;
        } else if (rowok && !a16 && k0 + skq + 7 < K) {
            // 8-byte aligned path (lda even, e.g. 498)
#pragma unroll
            for (int j = 0; j < 8; j += 2) {
                float2 t = *(const float2*)(ap + j);
                va[j] = t.x; va[j + 1] = t.y;
            }
        } else {
#pragma unroll
            for (int j = 0; j < 8; ++j)
                va[j] = (rowok && k0 + skq + j < K) ? ap[j] : 0.f;
        }
        bf16x8 ab;
#pragma unroll
        for (int j = 0; j < 8; ++j) ab[j] = (__bf16)va[j];
        *(bf16x8*)&As[srow][skq] = ab;
        // ---- stage B (bf16 W^T) ----
        bf16x8 bb = *(const bf16x8*)(WT + (long long)(n0 + srow) * kpad + k0 + skq);
        *(bf16x8*)&Bs[srow][skq] = bb;

        __syncthreads();
        bf16x8 bfr[2];
#pragma unroll
        for (int j = 0; j < 2; ++j)
            bfr[j] = *(const bf16x8*)&Bs[wn * 32 + j * 16 + fm][kgrp * 8];
#pragma unroll
        for (int i = 0; i < 2; ++i) {
            bf16x8 af = *(const bf16x8*)&As[wm * 32 + i * 16 + fm][kgrp * 8];
#pragma unroll
            for (int j = 0; j < 2; ++j)
                acc[i][j] = __builtin_amdgcn_mfma_f32_16x16x32_bf16(af, bfr[j], acc[i][j], 0, 0, 0);
        }
        __syncthreads();
    }

    // ---- epilogue ----
    int rbase = (lane >> 4) * 4;
    int ccol = lane & 15;
#pragma unroll
    for (int i = 0; i < 2; ++i) {
#pragma unroll
        for (int r = 0; r < 4; ++r) {
            int gm = m0 + wm * 32 + i * 16 + rbase + r;
            if (gm >= len) continue;
#pragma unroll
            for (int j = 0; j < 2; ++j) {
                int gn = n0 + wn * 32 + j * 16 + ccol;
                float v = acc[i][j][r] + bias[gn];
                if (flags & F_POSEMB) v += modv[gn] + posm[(long long)gm * FEAT + gn];
                if (flags & F_POS0)   v += modv[gn] + posm[gn];
                if (flags & F_RESID)  v += resid[(long long)z * resStrideZ + (long long)gm * ldc + gn];
                if (flags & F_GELU)   v = 0.5f * v * (1.f + erff(v * 0.70710678118654752f));
                Cz[(long long)gm * ldc + gn] = v;
            }
        }
    }
}

// ---------------------------------------------------------------------------
// Flash attention, 8-lanes-per-query (round-3 version, fp32).
// ---------------------------------------------------------------------------
__global__ __launch_bounds__(256) void attn_kernel(
    const float* __restrict__ qkv, float* __restrict__ o,
    const int* __restrict__ seqlen)
{
    int n = blockIdx.z, h = blockIdx.y, qt = blockIdx.x;
    int len = (n & 1) ? 1 : seqlen[n >> 1];
    int q0 = qt * 32;
    if (q0 >= len) return;
    int tid = threadIdx.x;
    int qloc = tid >> 3;
    int g = tid & 7;
    int qi = q0 + qloc;
    bool act = qi < len;

    const float* base = qkv + (long long)n * TLEN * 768;
    const float* qrow = base + (long long)(act ? qi : q0) * 768 + h * HD;
    float qreg[32];
#pragma unroll
    for (int d = 0; d < 32; d += 4) {
        float4 v = *(const float4*)(qrow + d);
        qreg[d] = v.x; qreg[d + 1] = v.y; qreg[d + 2] = v.z; qreg[d + 3] = v.w;
    }

    const float scale = 0.17677669529663687f; // 1/sqrt(32)
    float m = -1e30f, l = 0.f;
    float acc[32];
#pragma unroll
    for (int d = 0; d < 32; d++) acc[d] = 0.f;

    __shared__ float Ks[64][36];
    __shared__ float Vs[64][36];

    for (int k0 = 0; k0 < len; k0 += 64) {
        int kend = min(64, len - k0);
        __syncthreads();
#pragma unroll
        for (int i = 0; i < 2; ++i) {
            int idx = tid + i * 256;
            int row = idx >> 3, c = (idx & 7) * 4;
            if (row < kend) {
                const float* kr = base + (long long)(k0 + row) * 768 + 256 + h * HD;
                *(float4*)&Ks[row][c] = *(const float4*)(kr + c);
                *(float4*)&Vs[row][c] = *(const float4*)(kr + 256 + c);
            }
        }
        __syncthreads();

        float s[8];
        float tm = -1e30f;
#pragma unroll
        for (int j = 0; j < 8; ++j) {
            int key = g + 8 * j;
            float d0 = 0.f;
            if (key < kend) {
                const float* kr = &Ks[key][0];
#pragma unroll
                for (int d = 0; d < 32; d += 4) {
                    float4 kv = *(const float4*)(kr + d);
                    d0 += qreg[d] * kv.x + qreg[d + 1] * kv.y
                        + qreg[d + 2] * kv.z + qreg[d + 3] * kv.w;
                }
                s[j] = d0 * scale;
                tm = fmaxf(tm, s[j]);
            } else {
                s[j] = -1e30f;
            }
        }
        if (tm > m) {
            float corr = __expf(m - tm);
            l *= corr;
#pragma unroll
            for (int d = 0; d < 32; d++) acc[d] *= corr;
            m = tm;
        }
#pragma unroll
        for (int j = 0; j < 8; ++j) {
            int key = g + 8 * j;
            if (key < kend) {
                float p = __expf(s[j] - m);
                l += p;
                const float* vr = &Vs[key][0];
#pragma unroll
                for (int d = 0; d < 32; d += 4) {
                    float4 vv = *(const float4*)(vr + d);
                    acc[d]     += p * vv.x; acc[d + 1] += p * vv.y;
                    acc[d + 2] += p * vv.z; acc[d + 3] += p * vv.w;
                }
            }
        }
    }

#pragma unroll
    for (int off = 1; off < 8; off <<= 1) {
        float mo = __shfl_xor(m, off);
        float lo = __shfl_xor(l, off);
        float mn = fmaxf(m, mo);
        float fs = __expf(m - mn);
        float fo = __expf(mo - mn);
        l = l * fs + lo * fo;
#pragma unroll
        for (int d = 0; d < 32; d++) {
            float ao = __shfl_xor(acc[d], off);
            acc[d] = acc[d] * fs + ao * fo;
        }
        m = mn;
    }

    if (act) {
        float inv = 1.f / l;
        float* orow = o + ((long long)n * TLEN + qi) * FEAT + h * HD;
#pragma unroll
        for (int d0 = 0; d0 < 8; ++d0) {
            if (g == d0) {
                float4 v;
                v.x = acc[4 * d0 + 0] * inv; v.y = acc[4 * d0 + 1] * inv;
                v.z = acc[4 * d0 + 2] * inv; v.w = acc[4 * d0 + 3] * inv;
                *(float4*)(orow + 4 * d0) = v;
            }
        }
    }
}

// ---------------------------------------------------------------------------
// LayerNorm over last dim (256), one wave per valid token row.
// ---------------------------------------------------------------------------
__global__ __launch_bounds__(64) void ln_kernel(
    const float* __restrict__ tmp, float* __restrict__ x,
    const float* __restrict__ g, const float* __restrict__ b,
    const int* __restrict__ seqlen)
{
    int t = blockIdx.x, n = blockIdx.y;
    int len = (n & 1) ? 1 : seqlen[n >> 1];
    if (t >= len) return;
    int tid = threadIdx.x;
    const float* row = tmp + ((long long)n * TLEN + t) * FEAT;
    int f = tid * 4;
    float4 v = *(const float4*)(row + f);
    float s = v.x + v.y + v.z + v.w;
#pragma unroll
    for (int off = 32; off; off >>= 1) s += __shfl_down(s, off);
    float mu = __shfl(s, 0) * (1.f / 256.f);
    float dx = v.x - mu, dy = v.y - mu, dz = v.z - mu, dw = v.w - mu;
    float q = dx * dx + dy * dy + dz * dz + dw * dw;
#pragma unroll
    for (int off = 32; off; off >>= 1) q += __shfl_down(q, off);
    float var = __shfl(q, 0) * (1.f / 256.f);
    float r = rsqrtf(var + 1e-5f);
    float4 ov;
    ov.x = dx * r * g[f + 0] + b[f + 0];
    ov.y = dy * r * g[f + 1] + b[f + 1];
    ov.z = dz * r * g[f + 2] + b[f + 2];
    ov.w = dw * r * g[f + 3] + b[f + 3];
    *(float4*)(x + ((long long)n * TLEN + t) * FEAT + f) = ov;
}

// ---------------------------------------------------------------------------
// Masked mean-pool + output projection (x2 outputs). valid_cxr is int32.
// Block = 1024 threads = 4 token/k groups x 256 features; LDS tree-reduce
// between phases. Replaces the 119 us latency-bound serial version.
// ---------------------------------------------------------------------------
__global__ __launch_bounds__(1024) void pool_out_kernel(
    const float* __restrict__ x, const float* __restrict__ W,
    const float* __restrict__ b, const int* __restrict__ seqlen,
    const int* __restrict__ valid_cxr, float* __restrict__ out)
{
    int n = blockIdx.x;
    int tid = threadIdx.x;
    int f = tid & 255;
    int tg = tid >> 8;               // 0..3
    int cnt = (n & 1) ? (valid_cxr[n >> 1] != 0 ? 1 : 0) : seqlen[n >> 1];

    __shared__ float part[4][FEAT];
    __shared__ float pooled[FEAT];

    // ---- token sum: group tg handles t = tg, tg+4, ... (2-deep unroll) ----
    const float* xb = x + (long long)n * TLEN * FEAT + f;
    float s0 = 0.f, s1 = 0.f;
    int t = tg;
    for (; t + 4 < cnt; t += 8) {
        s0 += xb[(long long)t * FEAT];
        s1 += xb[(long long)(t + 4) * FEAT];
    }
    if (t < cnt) s0 += xb[(long long)t * FEAT];
    part[tg][f] = s0 + s1;
    __syncthreads();
    if (tg == 0) {
        float v = part[0][f] + part[1][f] + part[2][f] + part[3][f];
        pooled[f] = cnt ? v / (float)cnt : 0.f;
    }
    __syncthreads();

    // ---- projection: group tg sums k in [tg*64, tg*64+64) ----
    float acc = 0.f;
    const float* wcol = W + f;
#pragma unroll 8
    for (int k = tg * 64; k < tg * 64 + 64; ++k)
        acc += pooled[k] * wcol[(long long)k * FEAT];
    __syncthreads();   // part[][] read above is done (pooled phase separated it)
    part[tg][f] = acc;
    __syncthreads();
    if (tg == 0) {
        float v = part[0][f] + part[1][f] + part[2][f] + part[3][f] + b[f];
        out[(long long)n * FEAT + f] = v;
        out[NROWS * FEAT + (long long)n * FEAT + f] = v;
    }
}

// ---------------------------------------------------------------------------
extern "C" void kernel_launch(void* const* d_in, const int* in_sizes, int n_in,
                              void* d_out, int out_size, void* d_ws, size_t ws_size,
                              hipStream_t stream)
{
    const float* ehr_data = (const float*)d_in[0];
    const float* cxr_data = (const float*)d_in[1];
    const int*   seqlen   = (const int*)d_in[2];
    const int*   valid_cxr = (const int*)d_in[3];
    const float* ehr_w = (const float*)d_in[4];
    const float* ehr_b = (const float*)d_in[5];
    const float* cxr_w = (const float*)d_in[6];
    const float* cxr_b = (const float*)d_in[7];
    const float* modemb = (const float*)d_in[8];
    const float* pos    = (const float*)d_in[9];
    const float* qkv_w  = (const float*)d_in[10];
    const float* qkv_b  = (const float*)d_in[11];
    const float* aow    = (const float*)d_in[12];
    const float* aob    = (const float*)d_in[13];
    const float* ln1g   = (const float*)d_in[14];
    const float* ln1b   = (const float*)d_in[15];
    const float* ln2g   = (const float*)d_in[16];
    const float* ln2b   = (const float*)d_in[17];
    const float* ff1w   = (const float*)d_in[18];
    const float* ff1b   = (const float*)d_in[19];
    const float* ff2w   = (const float*)d_in[20];
    const float* ff2b   = (const float*)d_in[21];
    const float* outw   = (const float*)d_in[22];
    const float* outb   = (const float*)d_in[23];
    float* out = (float*)d_out;

    float* ws   = (float*)d_ws;
    float* x    = ws;                  // 32*501*256  = 4,104,192 floats
    float* qkv  = ws + 4104192;        // 32*501*768  = 12,312,576 floats
    float* obuf = ws + 16416768;       // 32*501*256
    float* tmp  = ws + 20520960;       // 32*501*256
    float* h    = qkv;                 // 32*501*1024 overlays qkv+obuf
    __bf16* wb  = (__bf16*)(ws + 24625152);  // bf16 W^T pool: 3,014,656 elems (~6 MB)

    // ---- weight conversion descriptors (bf16 W^T[N][Kpad]) ----
    WPack p;
    unsigned off = 0;
    p.d[0] = { ehr_w, off, EHR_IN, FEAT, 512 };            off += 256 * 512;
    unsigned qkvOff = off;
    for (int l = 0; l < 3; ++l) { p.d[1 + l] = { qkv_w + (long long)l * FEAT * 768, off, FEAT, 768, FEAT };  off += 768 * FEAT; }
    unsigned aoOff = off;
    for (int l = 0; l < 3; ++l) { p.d[4 + l] = { aow + (long long)l * FEAT * FEAT, off, FEAT, FEAT, FEAT };  off += FEAT * FEAT; }
    unsigned ff1Off = off;
    for (int l = 0; l < 3; ++l) { p.d[7 + l] = { ff1w + (long long)l * FEAT * FFDIM, off, FEAT, FFDIM, FEAT }; off += FFDIM * FEAT; }
    unsigned ff2Off = off;
    for (int l = 0; l < 3; ++l) { p.d[10 + l] = { ff2w + (long long)l * FFDIM * FEAT, off, FFDIM, FEAT, FFDIM }; off += FEAT * FFDIM; }
    unsigned cxrOff = off;
    p.d[13] = { cxr_w, off, CXR_IN, FEAT, CXR_IN };        off += FEAT * CXR_IN;

    wconv_kernel<<<dim3(32, 64, 14), 256, 0, stream>>>(p, wb);

    // ehr projection -> even rows of x
    gemm_mfma<<<dim3(8, 4, 16), 256, 0, stream>>>(
        ehr_data, EHR_IN, (long long)MAXLEN * EHR_IN, MAXLEN,
        wb + 0, 512, EHR_IN,
        x, FEAT, (long long)2 * TLEN * FEAT,
        ehr_b, nullptr, 0, modemb /*row0*/, pos, seqlen, 0, F_POSEMB);
    // cxr projection -> odd rows token 0 (M=16 dense GEMM, strided C rows)
    gemm_mfma<<<dim3(1, 4, 1), 256, 0, stream>>>(
        cxr_data, CXR_IN, 0, BATCH,
        wb + cxrOff, CXR_IN, CXR_IN,
        x + (long long)TLEN * FEAT, 2 * TLEN * FEAT, 0,
        cxr_b, nullptr, 0, modemb + FEAT, pos, seqlen, 2, F_POS0);

    for (int l = 0; l < NLAYERS; ++l) {
        gemm_mfma<<<dim3(8, 12, 32), 256, 0, stream>>>(
            x, FEAT, (long long)TLEN * FEAT, TLEN,
            wb + qkvOff + (long long)l * 768 * FEAT, FEAT, FEAT,
            qkv, 3 * FEAT, (long long)TLEN * 3 * FEAT,
            qkv_b + (long long)l * 3 * FEAT, nullptr, 0, nullptr, nullptr, seqlen, 1, 0);

        attn_kernel<<<dim3(16, NHEAD, NROWS), 256, 0, stream>>>(qkv, obuf, seqlen);

        gemm_mfma<<<dim3(8, 4, 32), 256, 0, stream>>>(
            obuf, FEAT, (long long)TLEN * FEAT, TLEN,
            wb + aoOff + (long long)l * FEAT * FEAT, FEAT, FEAT,
            tmp, FEAT, (long long)TLEN * FEAT,
            aob + (long long)l * FEAT, x, (long long)TLEN * FEAT, nullptr, nullptr, seqlen, 1, F_RESID);

        ln_kernel<<<dim3(TLEN, NROWS), 64, 0, stream>>>(
            tmp, x, ln1g + l * FEAT, ln1b + l * FEAT, seqlen);

        gemm_mfma<<<dim3(8, 16, 32), 256, 0, stream>>>(
            x, FEAT, (long long)TLEN * FEAT, TLEN,
            wb + ff1Off + (long long)l * FFDIM * FEAT, FEAT, FEAT,
            h, FFDIM, (long long)TLEN * FFDIM,
            ff1b + (long long)l * FFDIM, nullptr, 0, nullptr, nullptr, seqlen, 1, F_GELU);

        gemm_mfma<<<dim3(8, 4, 32), 256, 0, stream>>>(
            h, FFDIM, (long long)TLEN * FFDIM, TLEN,
            wb + ff2Off + (long long)l * FEAT * FFDIM, FFDIM, FFDIM,
            tmp, FEAT, (long long)TLEN * FEAT,
            ff2b + (long long)l * FEAT, x, (long long)TLEN * FEAT, nullptr, nullptr, seqlen, 1, F_RESID);

        ln_kernel<<<dim3(TLEN, NROWS), 64, 0, stream>>>(
            tmp, x, ln2g + l * FEAT, ln2b + l * FEAT, seqlen);
    }

    pool_out_kernel<<<NROWS, 1024, 0, stream>>>(x, outw, outb, seqlen, valid_cxr, out);
}

// Round 6
// 611.935 us; speedup vs baseline: 3.0006x; 1.1258x over previous
//
#include <hip/hip_runtime.h>
#include <math.h>

#define FEAT 256
#define NHEAD 8
#define HD 32
#define NLAYERS 3
#define EHR_IN 498
#define MAXLEN 500
#define BATCH 16
#define CXR_IN 2048
#define FFDIM 1024
#define NROWS 32
#define TLEN 501

#define F_GELU 1
#define F_RESID 2
#define F_POSEMB 4
#define F_POS0 8

typedef __bf16 bf16x8 __attribute__((ext_vector_type(8)));
typedef __bf16 bf16x4 __attribute__((ext_vector_type(4)));
typedef float f32x4 __attribute__((ext_vector_type(4)));

// ---------------------------------------------------------------------------
// Weight prep: fp32 W[K][N] -> bf16 W^T[N][Kpad] (zero-padded K), all
// matrices in one dispatch. 32x32 tiles via LDS.
// ---------------------------------------------------------------------------
struct WDesc { const float* src; unsigned dstOff; int K, N, Kpad; };
struct WPack { WDesc d[14]; };

__global__ __launch_bounds__(256) void wconv_kernel(WPack p, __bf16* __restrict__ wb)
{
    WDesc w = p.d[blockIdx.z];
    int n0 = blockIdx.x * 32, k0 = blockIdx.y * 32;
    if (n0 >= w.N || k0 >= w.Kpad) return;
    __shared__ float t[32][33];
    int tid = threadIdx.x;
    int c = tid & 31, r = tid >> 5;
#pragma unroll
    for (int i = 0; i < 4; ++i) {
        int k = k0 + r + i * 8;
        int n = n0 + c;
        t[r + i * 8][c] = (k < w.K && n < w.N) ? w.src[(long long)k * w.N + n] : 0.f;
    }
    __syncthreads();
    int nl = tid >> 3, kq = (tid & 7) * 4;
    int n = n0 + nl;
    if (n < w.N) {
        bf16x4 v;
#pragma unroll
        for (int j = 0; j < 4; ++j) v[j] = (__bf16)t[kq + j][nl];
        *(bf16x4*)(wb + w.dstOff + (long long)n * w.Kpad + k0 + kq) = v;
    }
}

// ---------------------------------------------------------------------------
// bf16 MFMA GEMM (validated round 4). Tile 64x64, BK=32, 4 waves 2x2 frags.
// Fragment layouts: A: m=lane&15, k=(lane>>4)*8+j ; B: n=lane&15, same k
//                   C/D: col=lane&15, row=(lane>>4)*4+reg
// lenMode: 0 = seq[z], 1 = interleaved token rows, 2 = dense (len = Mrows).
// ---------------------------------------------------------------------------
__global__ __launch_bounds__(256) void gemm_mfma(
    const float* __restrict__ A, int lda, long long aStrideZ, int Mrows,
    const __bf16* __restrict__ WT, int kpad, int K,
    float* __restrict__ C, int ldc, long long cStrideZ,
    const float* __restrict__ bias,
    const float* __restrict__ resid, long long resStrideZ,
    const float* __restrict__ modv, const float* __restrict__ posm,
    const int* __restrict__ seqlen, int lenMode, int flags)
{
    int z = blockIdx.z;
    int len = (lenMode == 2) ? Mrows
            : (lenMode == 0) ? seqlen[z]
            : ((z & 1) ? 1 : seqlen[z >> 1]);
    int m0 = blockIdx.x * 64;
    if (m0 >= len) return;
    int n0 = blockIdx.y * 64;

    const float* Az = A + (long long)z * aStrideZ;
    float* Cz = C + (long long)z * cStrideZ;

    __shared__ __bf16 As[64][40];
    __shared__ __bf16 Bs[64][40];

    int tid = threadIdx.x;
    int wave = tid >> 6, lane = tid & 63;
    int wm = wave >> 1, wn = wave & 1;
    int fm = lane & 15, kgrp = lane >> 4;

    f32x4 acc[2][2];
#pragma unroll
    for (int i = 0; i < 2; ++i)
#pragma unroll
        for (int j = 0; j < 2; ++j)
#pragma unroll
            for (int r = 0; r < 4; ++r) acc[i][j][r] = 0.f;

    int srow = tid >> 2;
    int skq  = (tid & 3) * 8;
    int garow = m0 + srow;
    bool rowok = garow < Mrows;
    bool a16 = ((lda & 3) == 0);

    int nk = (K + 31) >> 5;
    for (int kt = 0; kt < nk; ++kt) {
        int k0 = kt << 5;
        float va[8];
        const float* ap = Az + (long long)garow * lda + k0 + skq;
        if (rowok && a16 && k0 + skq + 7 < K) {
            float4 t0 = *(const float4*)(ap);
            float4 t1 = *(const float4*)(ap + 4);
            va[0] = t0.x; va[1] = t0.y; va[2] = t0.z; va[3] = t0.w;
            va[4] = t1.x; va[5] = t1.y; va[6] = t1.z; va[7] = t1.w;
        } else if (rowok && !a16 && k0 + skq + 7 < K) {
#pragma unroll
            for (int j = 0; j < 8; j += 2) {
                float2 t = *(const float2*)(ap + j);
                va[j] = t.x; va[j + 1] = t.y;
            }
        } else {
#pragma unroll
            for (int j = 0; j < 8; ++j)
                va[j] = (rowok && k0 + skq + j < K) ? ap[j] : 0.f;
        }
        bf16x8 ab;
#pragma unroll
        for (int j = 0; j < 8; ++j) ab[j] = (__bf16)va[j];
        *(bf16x8*)&As[srow][skq] = ab;
        bf16x8 bb = *(const bf16x8*)(WT + (long long)(n0 + srow) * kpad + k0 + skq);
        *(bf16x8*)&Bs[srow][skq] = bb;

        __syncthreads();
        bf16x8 bfr[2];
#pragma unroll
        for (int j = 0; j < 2; ++j)
            bfr[j] = *(const bf16x8*)&Bs[wn * 32 + j * 16 + fm][kgrp * 8];
#pragma unroll
        for (int i = 0; i < 2; ++i) {
            bf16x8 af = *(const bf16x8*)&As[wm * 32 + i * 16 + fm][kgrp * 8];
#pragma unroll
            for (int j = 0; j < 2; ++j)
                acc[i][j] = __builtin_amdgcn_mfma_f32_16x16x32_bf16(af, bfr[j], acc[i][j], 0, 0, 0);
        }
        __syncthreads();
    }

    int rbase = (lane >> 4) * 4;
    int ccol = lane & 15;
#pragma unroll
    for (int i = 0; i < 2; ++i) {
#pragma unroll
        for (int r = 0; r < 4; ++r) {
            int gm = m0 + wm * 32 + i * 16 + rbase + r;
            if (gm >= len) continue;
#pragma unroll
            for (int j = 0; j < 2; ++j) {
                int gn = n0 + wn * 32 + j * 16 + ccol;
                float v = acc[i][j][r] + bias[gn];
                if (flags & F_POSEMB) v += modv[gn] + posm[(long long)gm * FEAT + gn];
                if (flags & F_POS0)   v += modv[gn] + posm[gn];
                if (flags & F_RESID)  v += resid[(long long)z * resStrideZ + (long long)gm * ldc + gn];
                if (flags & F_GELU)   v = 0.5f * v * (1.f + erff(v * 0.70710678118654752f));
                Cz[(long long)gm * ldc + gn] = v;
            }
        }
    }
}

// ---------------------------------------------------------------------------
// MFMA flash attention.
// Block = 256 threads = 4 waves; wave w owns queries q0 + w*16 .. +15.
// Per 32-key tile (shared by all 4 waves via LDS, double-buffered):
//   S^T = mfma(K_frag, Q_frag)  -> lane holds 8 scores (8 keys) of ONE query
//   online softmax: in-lane reduce + shfl_xor(16,32)
//   P -> B-frag via 16 __shfl; O^T += mfma(V^T_frag, P_frag)
// LDS tiles are stored in FRAG-LINEAR order: staging thread c writes the
// 16B chunk that frag-reader lane c will ds_read_b128 at c*16 (conflict-free;
// the V transpose is absorbed into staging with 64B-coalesced gathers).
// Keys >= len masked to -3e38 by index after mfma; V rows >= len zeroed.
// ---------------------------------------------------------------------------
__global__ __launch_bounds__(256) void attn_mfma(
    const float* __restrict__ qkv, float* __restrict__ o,
    const int* __restrict__ seqlen)
{
    int n = blockIdx.z, h = blockIdx.y, qt = blockIdx.x;
    int len = (n & 1) ? 1 : seqlen[n >> 1];
    int q0 = qt * 64;
    if (q0 >= len) return;

    int tid = threadIdx.x;
    int wave = tid >> 6, lane = tid & 63;
    int fr = lane & 15, kg = lane >> 4;

    const float* base = qkv + (long long)n * TLEN * 768;
    const float scale = 0.17677669529663687f; // 1/sqrt(32)

    // ---- Q B-frag: query = q0+wave*16+fr (clamped), dims kg*8..+8 ----
    int qrow = q0 + wave * 16 + fr;
    if (qrow >= len) qrow = len - 1;
    bf16x8 qfrag;
    {
        const float* qp = base + (long long)qrow * 768 + h * HD + kg * 8;
        float4 t0 = *(const float4*)(qp);
        float4 t1 = *(const float4*)(qp + 4);
        qfrag[0] = (__bf16)t0.x; qfrag[1] = (__bf16)t0.y;
        qfrag[2] = (__bf16)t0.z; qfrag[3] = (__bf16)t0.w;
        qfrag[4] = (__bf16)t1.x; qfrag[5] = (__bf16)t1.y;
        qfrag[6] = (__bf16)t1.z; qfrag[7] = (__bf16)t1.w;
    }

    f32x4 po0 = {0.f, 0.f, 0.f, 0.f}, po1 = {0.f, 0.f, 0.f, 0.f};
    float m = -3.0e38f, l = 0.f;

    // [buf][chunk 0..255][8 bf16]: 0-63 Kfrag half0, 64-127 Kfrag half1,
    // 128-191 Vfrag dims0-15, 192-255 Vfrag dims16-31
    __shared__ __bf16 stage[2][256][8];

    int nt = (len + 31) >> 5;

    // staging as a lambda: thread tid fills chunk tid of buffer buf for tile t
    auto do_stage = [&](int t, int buf) {
        int k0 = t << 5;
        bf16x8 v;
        if (tid < 128) {
            int half = tid >> 6, cc = tid & 63;
            int key = k0 + half * 16 + (cc & 15);
            int dims = (cc >> 4) * 8;
            if (key < len) {
                const float* kp = base + (long long)key * 768 + 256 + h * HD + dims;
                float4 t0 = *(const float4*)(kp);
                float4 t1 = *(const float4*)(kp + 4);
                v[0] = (__bf16)t0.x; v[1] = (__bf16)t0.y; v[2] = (__bf16)t0.z; v[3] = (__bf16)t0.w;
                v[4] = (__bf16)t1.x; v[5] = (__bf16)t1.y; v[6] = (__bf16)t1.z; v[7] = (__bf16)t1.w;
            } else {
#pragma unroll
                for (int j = 0; j < 8; ++j) v[j] = (__bf16)0.f;
            }
        } else {
            int cc = tid & 63;
            int dim = ((tid >> 6) & 1) * 16 + (cc & 15);
            int keyb = k0 + (cc >> 4) * 8;
#pragma unroll
            for (int j = 0; j < 8; ++j) {
                int key = keyb + j;
                v[j] = (key < len) ? (__bf16)base[(long long)key * 768 + 512 + h * HD + dim]
                                   : (__bf16)0.f;
            }
        }
        *(bf16x8*)&stage[buf][tid][0] = v;
    };

    do_stage(0, 0);
    __syncthreads();

    for (int t = 0; t < nt; ++t) {
        int buf = t & 1;
        if (t + 1 < nt) do_stage(t + 1, buf ^ 1);

        int k0 = t << 5;
        bf16x8 kf0 = *(const bf16x8*)&stage[buf][lane][0];
        bf16x8 kf1 = *(const bf16x8*)&stage[buf][64 + lane][0];
        bf16x8 vf0 = *(const bf16x8*)&stage[buf][128 + lane][0];
        bf16x8 vf1 = *(const bf16x8*)&stage[buf][192 + lane][0];

        f32x4 zero = {0.f, 0.f, 0.f, 0.f};
        f32x4 s0 = __builtin_amdgcn_mfma_f32_16x16x32_bf16(kf0, qfrag, zero, 0, 0, 0);
        f32x4 s1 = __builtin_amdgcn_mfma_f32_16x16x32_bf16(kf1, qfrag, zero, 0, 0, 0);

        // mask + scale (by index; NaN-proof)
        float sc[8];
#pragma unroll
        for (int r = 0; r < 4; ++r) {
            int keyA = k0 + kg * 4 + r;
            int keyB = k0 + 16 + kg * 4 + r;
            sc[r]     = (keyA < len) ? s0[r] * scale : -3.0e38f;
            sc[4 + r] = (keyB < len) ? s1[r] * scale : -3.0e38f;
        }
        // tile max over 32 keys (in-lane 8 + cross-kg shuffles)
        float tm = sc[0];
#pragma unroll
        for (int i = 1; i < 8; ++i) tm = fmaxf(tm, sc[i]);
        tm = fmaxf(tm, __shfl_xor(tm, 16));
        tm = fmaxf(tm, __shfl_xor(tm, 32));
        float mn = fmaxf(m, tm);
        float corr = __expf(m - mn);
        l *= corr;
#pragma unroll
        for (int r = 0; r < 4; ++r) { po0[r] *= corr; po1[r] *= corr; }
        m = mn;

        float p[8];
        float lsum = 0.f;
#pragma unroll
        for (int i = 0; i < 8; ++i) { p[i] = __expf(sc[i] - m); lsum += p[i]; }
        lsum += __shfl_xor(lsum, 16);
        lsum += __shfl_xor(lsum, 32);
        l += lsum;

        // P redistribution -> B-frag (keys kg*8+{0..7}, query fr)
        int srcA = 16 * ((2 * kg) & 3) + fr;
        int srcB = 16 * ((2 * kg + 1) & 3) + fr;
        bool hi = (kg >> 1) != 0;   // need source's frag1 (keys 16..31)
        bf16x8 pf;
#pragma unroll
        for (int r = 0; r < 4; ++r) {
            float a0 = __shfl(p[r], srcA);
            float a1 = __shfl(p[4 + r], srcA);
            float b0 = __shfl(p[r], srcB);
            float b1 = __shfl(p[4 + r], srcB);
            pf[r]     = (__bf16)(hi ? a1 : a0);
            pf[4 + r] = (__bf16)(hi ? b1 : b0);
        }

        po0 = __builtin_amdgcn_mfma_f32_16x16x32_bf16(vf0, pf, po0, 0, 0, 0);
        po1 = __builtin_amdgcn_mfma_f32_16x16x32_bf16(vf1, pf, po1, 0, 0, 0);

        __syncthreads();
    }

    // ---- epilogue: lane holds O^T dims kg*4..+3 (and +16) for query fr ----
    int q = q0 + wave * 16 + fr;
    if (q < len) {
        float inv = 1.f / l;
        float* orow = o + ((long long)n * TLEN + q) * FEAT + h * HD;
        float4 w0, w1;
        w0.x = po0[0] * inv; w0.y = po0[1] * inv; w0.z = po0[2] * inv; w0.w = po0[3] * inv;
        w1.x = po1[0] * inv; w1.y = po1[1] * inv; w1.z = po1[2] * inv; w1.w = po1[3] * inv;
        *(float4*)(orow + kg * 4) = w0;
        *(float4*)(orow + 16 + kg * 4) = w1;
    }
}

// ---------------------------------------------------------------------------
// LayerNorm over last dim (256), one wave per valid token row.
// ---------------------------------------------------------------------------
__global__ __launch_bounds__(64) void ln_kernel(
    const float* __restrict__ tmp, float* __restrict__ x,
    const float* __restrict__ g, const float* __restrict__ b,
    const int* __restrict__ seqlen)
{
    int t = blockIdx.x, n = blockIdx.y;
    int len = (n & 1) ? 1 : seqlen[n >> 1];
    if (t >= len) return;
    int tid = threadIdx.x;
    const float* row = tmp + ((long long)n * TLEN + t) * FEAT;
    int f = tid * 4;
    float4 v = *(const float4*)(row + f);
    float s = v.x + v.y + v.z + v.w;
#pragma unroll
    for (int off = 32; off; off >>= 1) s += __shfl_down(s, off);
    float mu = __shfl(s, 0) * (1.f / 256.f);
    float dx = v.x - mu, dy = v.y - mu, dz = v.z - mu, dw = v.w - mu;
    float q = dx * dx + dy * dy + dz * dz + dw * dw;
#pragma unroll
    for (int off = 32; off; off >>= 1) q += __shfl_down(q, off);
    float var = __shfl(q, 0) * (1.f / 256.f);
    float r = rsqrtf(var + 1e-5f);
    float4 ov;
    ov.x = dx * r * g[f + 0] + b[f + 0];
    ov.y = dy * r * g[f + 1] + b[f + 1];
    ov.z = dz * r * g[f + 2] + b[f + 2];
    ov.w = dw * r * g[f + 3] + b[f + 3];
    *(float4*)(x + ((long long)n * TLEN + t) * FEAT + f) = ov;
}

// ---------------------------------------------------------------------------
// Masked mean-pool + output projection (x2 outputs). valid_cxr is int32.
// ---------------------------------------------------------------------------
__global__ __launch_bounds__(1024) void pool_out_kernel(
    const float* __restrict__ x, const float* __restrict__ W,
    const float* __restrict__ b, const int* __restrict__ seqlen,
    const int* __restrict__ valid_cxr, float* __restrict__ out)
{
    int n = blockIdx.x;
    int tid = threadIdx.x;
    int f = tid & 255;
    int tg = tid >> 8;
    int cnt = (n & 1) ? (valid_cxr[n >> 1] != 0 ? 1 : 0) : seqlen[n >> 1];

    __shared__ float part[4][FEAT];
    __shared__ float pooled[FEAT];

    const float* xb = x + (long long)n * TLEN * FEAT + f;
    float s0 = 0.f, s1 = 0.f;
    int t = tg;
    for (; t + 4 < cnt; t += 8) {
        s0 += xb[(long long)t * FEAT];
        s1 += xb[(long long)(t + 4) * FEAT];
    }
    if (t < cnt) s0 += xb[(long long)t * FEAT];
    part[tg][f] = s0 + s1;
    __syncthreads();
    if (tg == 0) {
        float v = part[0][f] + part[1][f] + part[2][f] + part[3][f];
        pooled[f] = cnt ? v / (float)cnt : 0.f;
    }
    __syncthreads();

    float acc = 0.f;
    const float* wcol = W + f;
#pragma unroll 8
    for (int k = tg * 64; k < tg * 64 + 64; ++k)
        acc += pooled[k] * wcol[(long long)k * FEAT];
    __syncthreads();
    part[tg][f] = acc;
    __syncthreads();
    if (tg == 0) {
        float v = part[0][f] + part[1][f] + part[2][f] + part[3][f] + b[f];
        out[(long long)n * FEAT + f] = v;
        out[NROWS * FEAT + (long long)n * FEAT + f] = v;
    }
}

// ---------------------------------------------------------------------------
extern "C" void kernel_launch(void* const* d_in, const int* in_sizes, int n_in,
                              void* d_out, int out_size, void* d_ws, size_t ws_size,
                              hipStream_t stream)
{
    const float* ehr_data = (const float*)d_in[0];
    const float* cxr_data = (const float*)d_in[1];
    const int*   seqlen   = (const int*)d_in[2];
    const int*   valid_cxr = (const int*)d_in[3];
    const float* ehr_w = (const float*)d_in[4];
    const float* ehr_b = (const float*)d_in[5];
    const float* cxr_w = (const float*)d_in[6];
    const float* cxr_b = (const float*)d_in[7];
    const float* modemb = (const float*)d_in[8];
    const float* pos    = (const float*)d_in[9];
    const float* qkv_w  = (const float*)d_in[10];
    const float* qkv_b  = (const float*)d_in[11];
    const float* aow    = (const float*)d_in[12];
    const float* aob    = (const float*)d_in[13];
    const float* ln1g   = (const float*)d_in[14];
    const float* ln1b   = (const float*)d_in[15];
    const float* ln2g   = (const float*)d_in[16];
    const float* ln2b   = (const float*)d_in[17];
    const float* ff1w   = (const float*)d_in[18];
    const float* ff1b   = (const float*)d_in[19];
    const float* ff2w   = (const float*)d_in[20];
    const float* ff2b   = (const float*)d_in[21];
    const float* outw   = (const float*)d_in[22];
    const float* outb   = (const float*)d_in[23];
    float* out = (float*)d_out;

    float* ws   = (float*)d_ws;
    float* x    = ws;                  // 32*501*256
    float* qkv  = ws + 4104192;        // 32*501*768
    float* obuf = ws + 16416768;       // 32*501*256
    float* tmp  = ws + 20520960;       // 32*501*256
    float* h    = qkv;                 // overlays qkv+obuf
    __bf16* wb  = (__bf16*)(ws + 24625152);  // bf16 W^T pool (~6 MB)

    WPack p;
    unsigned off = 0;
    p.d[0] = { ehr_w, off, EHR_IN, FEAT, 512 };            off += 256 * 512;
    unsigned qkvOff = off;
    for (int l = 0; l < 3; ++l) { p.d[1 + l] = { qkv_w + (long long)l * FEAT * 768, off, FEAT, 768, FEAT };  off += 768 * FEAT; }
    unsigned aoOff = off;
    for (int l = 0; l < 3; ++l) { p.d[4 + l] = { aow + (long long)l * FEAT * FEAT, off, FEAT, FEAT, FEAT };  off += FEAT * FEAT; }
    unsigned ff1Off = off;
    for (int l = 0; l < 3; ++l) { p.d[7 + l] = { ff1w + (long long)l * FEAT * FFDIM, off, FEAT, FFDIM, FEAT }; off += FFDIM * FEAT; }
    unsigned ff2Off = off;
    for (int l = 0; l < 3; ++l) { p.d[10 + l] = { ff2w + (long long)l * FFDIM * FEAT, off, FFDIM, FEAT, FFDIM }; off += FEAT * FFDIM; }
    unsigned cxrOff = off;
    p.d[13] = { cxr_w, off, CXR_IN, FEAT, CXR_IN };        off += FEAT * CXR_IN;

    wconv_kernel<<<dim3(32, 64, 14), 256, 0, stream>>>(p, wb);

    gemm_mfma<<<dim3(8, 4, 16), 256, 0, stream>>>(
        ehr_data, EHR_IN, (long long)MAXLEN * EHR_IN, MAXLEN,
        wb + 0, 512, EHR_IN,
        x, FEAT, (long long)2 * TLEN * FEAT,
        ehr_b, nullptr, 0, modemb, pos, seqlen, 0, F_POSEMB);
    gemm_mfma<<<dim3(1, 4, 1), 256, 0, stream>>>(
        cxr_data, CXR_IN, 0, BATCH,
        wb + cxrOff, CXR_IN, CXR_IN,
        x + (long long)TLEN * FEAT, 2 * TLEN * FEAT, 0,
        cxr_b, nullptr, 0, modemb + FEAT, pos, seqlen, 2, F_POS0);

    for (int l = 0; l < NLAYERS; ++l) {
        gemm_mfma<<<dim3(8, 12, 32), 256, 0, stream>>>(
            x, FEAT, (long long)TLEN * FEAT, TLEN,
            wb + qkvOff + (long long)l * 768 * FEAT, FEAT, FEAT,
            qkv, 3 * FEAT, (long long)TLEN * 3 * FEAT,
            qkv_b + (long long)l * 3 * FEAT, nullptr, 0, nullptr, nullptr, seqlen, 1, 0);

        attn_mfma<<<dim3(8, NHEAD, NROWS), 256, 0, stream>>>(qkv, obuf, seqlen);

        gemm_mfma<<<dim3(8, 4, 32), 256, 0, stream>>>(
            obuf, FEAT, (long long)TLEN * FEAT, TLEN,
            wb + aoOff + (long long)l * FEAT * FEAT, FEAT, FEAT,
            tmp, FEAT, (long long)TLEN * FEAT,
            aob + (long long)l * FEAT, x, (long long)TLEN * FEAT, nullptr, nullptr, seqlen, 1, F_RESID);

        ln_kernel<<<dim3(TLEN, NROWS), 64, 0, stream>>>(
            tmp, x, ln1g + l * FEAT, ln1b + l * FEAT, seqlen);

        gemm_mfma<<<dim3(8, 16, 32), 256, 0, stream>>>(
            x, FEAT, (long long)TLEN * FEAT, TLEN,
            wb + ff1Off + (long long)l * FFDIM * FEAT, FEAT, FEAT,
            h, FFDIM, (long long)TLEN * FFDIM,
            ff1b + (long long)l * FFDIM, nullptr, 0, nullptr, nullptr, seqlen, 1, F_GELU);

        gemm_mfma<<<dim3(8, 4, 32), 256, 0, stream>>>(
            h, FFDIM, (long long)TLEN * FFDIM, TLEN,
            wb + ff2Off + (long long)l * FEAT * FFDIM, FFDIM, FFDIM,
            tmp, FEAT, (long long)TLEN * FEAT,
            ff2b + (long long)l * FEAT, x, (long long)TLEN * FEAT, nullptr, nullptr, seqlen, 1, F_RESID);

        ln_kernel<<<dim3(TLEN, NROWS), 64, 0, stream>>>(
            tmp, x, ln2g + l * FEAT, ln2b + l * FEAT, seqlen);
    }

    pool_out_kernel<<<NROWS, 1024, 0, stream>>>(x, outw, outb, seqlen, valid_cxr, out);
}

// Round 7
// 554.871 us; speedup vs baseline: 3.3092x; 1.1028x over previous
//
#include <hip/hip_runtime.h>
#include <math.h>

#define FEAT 256
#define NHEAD 8
#define HD 32
#define NLAYERS 3
#define EHR_IN 498
#define MAXLEN 500
#define BATCH 16
#define CXR_IN 2048
#define FFDIM 1024
#define NROWS 32
#define TLEN 501

#define F_GELU 1
#define F_RESID 2
#define F_POSEMB 4
#define F_POS0 8

typedef __bf16 bf16x8 __attribute__((ext_vector_type(8)));
typedef __bf16 bf16x4 __attribute__((ext_vector_type(4)));
typedef float f32x4 __attribute__((ext_vector_type(4)));

// ---------------------------------------------------------------------------
// Weight prep: fp32 W[K][N] -> bf16 W^T[N][Kpad] (zero-padded K).
// ---------------------------------------------------------------------------
struct WDesc { const float* src; unsigned dstOff; int K, N, Kpad; };
struct WPack { WDesc d[14]; };

__global__ __launch_bounds__(256) void wconv_kernel(WPack p, __bf16* __restrict__ wb)
{
    WDesc w = p.d[blockIdx.z];
    int n0 = blockIdx.x * 32, k0 = blockIdx.y * 32;
    if (n0 >= w.N || k0 >= w.Kpad) return;
    __shared__ float t[32][33];
    int tid = threadIdx.x;
    int c = tid & 31, r = tid >> 5;
#pragma unroll
    for (int i = 0; i < 4; ++i) {
        int k = k0 + r + i * 8;
        int n = n0 + c;
        t[r + i * 8][c] = (k < w.K && n < w.N) ? w.src[(long long)k * w.N + n] : 0.f;
    }
    __syncthreads();
    int nl = tid >> 3, kq = (tid & 7) * 4;
    int n = n0 + nl;
    if (n < w.N) {
        bf16x4 v;
#pragma unroll
        for (int j = 0; j < 4; ++j) v[j] = (__bf16)t[kq + j][nl];
        *(bf16x4*)(wb + w.dstOff + (long long)n * w.Kpad + k0 + kq) = v;
    }
}

// ---------------------------------------------------------------------------
// bf16 MFMA GEMM (validated round 4). Tile 64x64, BK=32, 4 waves 2x2 frags.
// ---------------------------------------------------------------------------
__global__ __launch_bounds__(256) void gemm_mfma(
    const float* __restrict__ A, int lda, long long aStrideZ, int Mrows,
    const __bf16* __restrict__ WT, int kpad, int K,
    float* __restrict__ C, int ldc, long long cStrideZ,
    const float* __restrict__ bias,
    const float* __restrict__ resid, long long resStrideZ,
    const float* __restrict__ modv, const float* __restrict__ posm,
    const int* __restrict__ seqlen, int lenMode, int flags)
{
    int z = blockIdx.z;
    int len = (lenMode == 2) ? Mrows
            : (lenMode == 0) ? seqlen[z]
            : ((z & 1) ? 1 : seqlen[z >> 1]);
    int m0 = blockIdx.x * 64;
    if (m0 >= len) return;
    int n0 = blockIdx.y * 64;

    const float* Az = A + (long long)z * aStrideZ;
    float* Cz = C + (long long)z * cStrideZ;

    __shared__ __bf16 As[64][40];
    __shared__ __bf16 Bs[64][40];

    int tid = threadIdx.x;
    int wave = tid >> 6, lane = tid & 63;
    int wm = wave >> 1, wn = wave & 1;
    int fm = lane & 15, kgrp = lane >> 4;

    f32x4 acc[2][2];
#pragma unroll
    for (int i = 0; i < 2; ++i)
#pragma unroll
        for (int j = 0; j < 2; ++j)
#pragma unroll
            for (int r = 0; r < 4; ++r) acc[i][j][r] = 0.f;

    int srow = tid >> 2;
    int skq  = (tid & 3) * 8;
    int garow = m0 + srow;
    bool rowok = garow < Mrows;
    bool a16 = ((lda & 3) == 0);

    int nk = (K + 31) >> 5;
    for (int kt = 0; kt < nk; ++kt) {
        int k0 = kt << 5;
        float va[8];
        const float* ap = Az + (long long)garow * lda + k0 + skq;
        if (rowok && a16 && k0 + skq + 7 < K) {
            float4 t0 = *(const float4*)(ap);
            float4 t1 = *(const float4*)(ap + 4);
            va[0] = t0.x; va[1] = t0.y; va[2] = t0.z; va[3] = t0.w;
            va[4] = t1.x; va[5] = t1.y; va[6] = t1.z; va[7] = t1.w;
        } else if (rowok && !a16 && k0 + skq + 7 < K) {
#pragma unroll
            for (int j = 0; j < 8; j += 2) {
                float2 t = *(const float2*)(ap + j);
                va[j] = t.x; va[j + 1] = t.y;
            }
        } else {
#pragma unroll
            for (int j = 0; j < 8; ++j)
                va[j] = (rowok && k0 + skq + j < K) ? ap[j] : 0.f;
        }
        bf16x8 ab;
#pragma unroll
        for (int j = 0; j < 8; ++j) ab[j] = (__bf16)va[j];
        *(bf16x8*)&As[srow][skq] = ab;
        bf16x8 bb = *(const bf16x8*)(WT + (long long)(n0 + srow) * kpad + k0 + skq);
        *(bf16x8*)&Bs[srow][skq] = bb;

        __syncthreads();
        bf16x8 bfr[2];
#pragma unroll
        for (int j = 0; j < 2; ++j)
            bfr[j] = *(const bf16x8*)&Bs[wn * 32 + j * 16 + fm][kgrp * 8];
#pragma unroll
        for (int i = 0; i < 2; ++i) {
            bf16x8 af = *(const bf16x8*)&As[wm * 32 + i * 16 + fm][kgrp * 8];
#pragma unroll
            for (int j = 0; j < 2; ++j)
                acc[i][j] = __builtin_amdgcn_mfma_f32_16x16x32_bf16(af, bfr[j], acc[i][j], 0, 0, 0);
        }
        __syncthreads();
    }

    int rbase = (lane >> 4) * 4;
    int ccol = lane & 15;
#pragma unroll
    for (int i = 0; i < 2; ++i) {
#pragma unroll
        for (int r = 0; r < 4; ++r) {
            int gm = m0 + wm * 32 + i * 16 + rbase + r;
            if (gm >= len) continue;
#pragma unroll
            for (int j = 0; j < 2; ++j) {
                int gn = n0 + wn * 32 + j * 16 + ccol;
                float v = acc[i][j][r] + bias[gn];
                if (flags & F_POSEMB) v += modv[gn] + posm[(long long)gm * FEAT + gn];
                if (flags & F_POS0)   v += modv[gn] + posm[gn];
                if (flags & F_RESID)  v += resid[(long long)z * resStrideZ + (long long)gm * ldc + gn];
                if (flags & F_GELU)   v = 0.5f * v * (1.f + erff(v * 0.70710678118654752f));
                Cz[(long long)gm * ldc + gn] = v;
            }
        }
    }
}

// ---------------------------------------------------------------------------
// MFMA flash attention, 64-key tiles, ZERO P-redistribution shuffles.
// Key trick: K-frag f's key order is PERMUTED at staging:
//   a_f(m) = (m>>2)*8 + (f&1)*4 + (m&3) + (f>>1)*32
// so QK^T score regs land exactly in PV B-frag order in-lane:
//   p[f*4+r] corresponds to key kg*8 + j with pf0=p[0..7], pf1=p[8..15].
// LDS chunks (bf16x8) in pad-17 frag-linear layout: chunk(f,kg,m)=(f*4+kg)*17+m
// (K region 272 chunks, V region 272: Voff(sh,kg,m)=272+(sh*4+kg)*17+m,
//  sh = keyblock*2 + dimhalf). Double-buffered; one barrier per 64 keys.
// ---------------------------------------------------------------------------
__global__ __launch_bounds__(256) void attn_mfma(
    const float* __restrict__ qkv, float* __restrict__ o,
    const int* __restrict__ seqlen)
{
    int n = blockIdx.z, h = blockIdx.y, qt = blockIdx.x;
    int len = (n & 1) ? 1 : seqlen[n >> 1];
    int q0 = qt * 64;
    if (q0 >= len) return;

    int tid = threadIdx.x;
    int wave = tid >> 6, lane = tid & 63;
    int fr = lane & 15, kg = lane >> 4;

    const float* base = qkv + (long long)n * TLEN * 768;
    const float scale = 0.17677669529663687f; // 1/sqrt(32)

    // ---- Q B-frag: query q0+wave*16+fr (clamped), dims kg*8..+7 ----
    int qrow = q0 + wave * 16 + fr;
    if (qrow >= len) qrow = len - 1;
    bf16x8 qfrag;
    {
        const float* qp = base + (long long)qrow * 768 + h * HD + kg * 8;
        float4 t0 = *(const float4*)(qp);
        float4 t1 = *(const float4*)(qp + 4);
        qfrag[0] = (__bf16)t0.x; qfrag[1] = (__bf16)t0.y;
        qfrag[2] = (__bf16)t0.z; qfrag[3] = (__bf16)t0.w;
        qfrag[4] = (__bf16)t1.x; qfrag[5] = (__bf16)t1.y;
        qfrag[6] = (__bf16)t1.z; qfrag[7] = (__bf16)t1.w;
    }

    f32x4 po0 = {0.f, 0.f, 0.f, 0.f}, po1 = {0.f, 0.f, 0.f, 0.f};
    float m = -3.0e38f, l = 0.f;

    __shared__ bf16x8 stage[2][544];   // 2 x 8704 B

    // staging roles (tid -> one K chunk + one V chunk)
    int f_    = tid >> 6;
    int kgrp_ = (tid >> 4) & 3;
    int mm_   = tid & 15;
    int kKeyL  = ((mm_ >> 2) << 3) + ((f_ & 1) << 2) + (mm_ & 3) + ((f_ >> 1) << 5);
    int kChunk = (f_ * 4 + kgrp_) * 17 + mm_;
    int vDim   = ((f_ & 1) << 4) + mm_;              // sh=f_: dim half + local
    int vKeyB  = ((f_ >> 1) << 5) + (kgrp_ << 3);    // keyblock*32 + kg*8
    int vChunk = 272 + (f_ * 4 + kgrp_) * 17 + mm_;

    int nt = (len + 63) >> 6;

    auto do_stage = [&](int t, int buf) {
        int k0 = t << 6;
        // K chunk: 8 dims of one (permuted) key
        bf16x8 kv;
        int key = k0 + kKeyL;
        if (key < len) {
            const float* kp = base + (long long)key * 768 + 256 + h * HD + kgrp_ * 8;
            float4 t0 = *(const float4*)(kp);
            float4 t1 = *(const float4*)(kp + 4);
            kv[0] = (__bf16)t0.x; kv[1] = (__bf16)t0.y; kv[2] = (__bf16)t0.z; kv[3] = (__bf16)t0.w;
            kv[4] = (__bf16)t1.x; kv[5] = (__bf16)t1.y; kv[6] = (__bf16)t1.z; kv[7] = (__bf16)t1.w;
        } else {
#pragma unroll
            for (int j = 0; j < 8; ++j) kv[j] = (__bf16)0.f;
        }
        stage[buf][kChunk] = kv;
        // V chunk: dim vDim of 8 consecutive keys (64B-coalesced across lanes)
        bf16x8 vv;
#pragma unroll
        for (int j = 0; j < 8; ++j) {
            int vkey = k0 + vKeyB + j;
            vv[j] = (vkey < len) ? (__bf16)base[(long long)vkey * 768 + 512 + h * HD + vDim]
                                 : (__bf16)0.f;
        }
        stage[buf][vChunk] = vv;
    };

    do_stage(0, 0);
    __syncthreads();

    for (int t = 0; t < nt; ++t) {
        int buf = t & 1;
        if (t + 1 < nt) do_stage(t + 1, buf ^ 1);

        int k0 = t << 6;
        bf16x8 kf0 = stage[buf][(0 * 4 + kg) * 17 + fr];
        bf16x8 kf1 = stage[buf][(1 * 4 + kg) * 17 + fr];
        bf16x8 kf2 = stage[buf][(2 * 4 + kg) * 17 + fr];
        bf16x8 kf3 = stage[buf][(3 * 4 + kg) * 17 + fr];

        f32x4 zero = {0.f, 0.f, 0.f, 0.f};
        f32x4 s0 = __builtin_amdgcn_mfma_f32_16x16x32_bf16(kf0, qfrag, zero, 0, 0, 0);
        f32x4 s1 = __builtin_amdgcn_mfma_f32_16x16x32_bf16(kf1, qfrag, zero, 0, 0, 0);
        f32x4 s2 = __builtin_amdgcn_mfma_f32_16x16x32_bf16(kf2, qfrag, zero, 0, 0, 0);
        f32x4 s3 = __builtin_amdgcn_mfma_f32_16x16x32_bf16(kf3, qfrag, zero, 0, 0, 0);

        // mask+scale; p index i=f*4+r <-> key k0 + kg*8 + (f&1)*4 + r + (f>>1)*32
        float sc[16];
        int kb = k0 + kg * 8;
#pragma unroll
        for (int r = 0; r < 4; ++r) {
            sc[r]      = (kb + r < len)      ? s0[r] * scale : -3.0e38f;
            sc[4 + r]  = (kb + 4 + r < len)  ? s1[r] * scale : -3.0e38f;
            sc[8 + r]  = (kb + 32 + r < len) ? s2[r] * scale : -3.0e38f;
            sc[12 + r] = (kb + 36 + r < len) ? s3[r] * scale : -3.0e38f;
        }
        float tm = sc[0];
#pragma unroll
        for (int i = 1; i < 16; ++i) tm = fmaxf(tm, sc[i]);
        tm = fmaxf(tm, __shfl_xor(tm, 16));
        tm = fmaxf(tm, __shfl_xor(tm, 32));
        float mn = fmaxf(m, tm);
        float corr = __expf(m - mn);
        l *= corr;
#pragma unroll
        for (int r = 0; r < 4; ++r) { po0[r] *= corr; po1[r] *= corr; }
        m = mn;

        float p[16];
        float lsum = 0.f;
#pragma unroll
        for (int i = 0; i < 16; ++i) { p[i] = __expf(sc[i] - m); lsum += p[i]; }
        lsum += __shfl_xor(lsum, 16);
        lsum += __shfl_xor(lsum, 32);
        l += lsum;

        bf16x8 pf0, pf1;
#pragma unroll
        for (int j = 0; j < 8; ++j) { pf0[j] = (__bf16)p[j]; pf1[j] = (__bf16)p[8 + j]; }

        bf16x8 vf00 = stage[buf][272 + (0 * 4 + kg) * 17 + fr]; // keys 0-31, dims 0-15
        bf16x8 vf01 = stage[buf][272 + (1 * 4 + kg) * 17 + fr]; // keys 0-31, dims16-31
        bf16x8 vf10 = stage[buf][272 + (2 * 4 + kg) * 17 + fr]; // keys32-63, dims 0-15
        bf16x8 vf11 = stage[buf][272 + (3 * 4 + kg) * 17 + fr]; // keys32-63, dims16-31

        po0 = __builtin_amdgcn_mfma_f32_16x16x32_bf16(vf00, pf0, po0, 0, 0, 0);
        po0 = __builtin_amdgcn_mfma_f32_16x16x32_bf16(vf10, pf1, po0, 0, 0, 0);
        po1 = __builtin_amdgcn_mfma_f32_16x16x32_bf16(vf01, pf0, po1, 0, 0, 0);
        po1 = __builtin_amdgcn_mfma_f32_16x16x32_bf16(vf11, pf1, po1, 0, 0, 0);

        __syncthreads();
    }

    // ---- epilogue: lane holds O^T dims kg*4..+3 (po0) and 16+kg*4..+3 (po1)
    int q = q0 + wave * 16 + fr;
    if (q < len) {
        float inv = 1.f / l;
        float* orow = o + ((long long)n * TLEN + q) * FEAT + h * HD;
        float4 w0, w1;
        w0.x = po0[0] * inv; w0.y = po0[1] * inv; w0.z = po0[2] * inv; w0.w = po0[3] * inv;
        w1.x = po1[0] * inv; w1.y = po1[1] * inv; w1.z = po1[2] * inv; w1.w = po1[3] * inv;
        *(float4*)(orow + kg * 4) = w0;
        *(float4*)(orow + 16 + kg * 4) = w1;
    }
}

// ---------------------------------------------------------------------------
// LayerNorm over last dim (256), one wave per valid token row.
// ---------------------------------------------------------------------------
__global__ __launch_bounds__(64) void ln_kernel(
    const float* __restrict__ tmp, float* __restrict__ x,
    const float* __restrict__ g, const float* __restrict__ b,
    const int* __restrict__ seqlen)
{
    int t = blockIdx.x, n = blockIdx.y;
    int len = (n & 1) ? 1 : seqlen[n >> 1];
    if (t >= len) return;
    int tid = threadIdx.x;
    const float* row = tmp + ((long long)n * TLEN + t) * FEAT;
    int f = tid * 4;
    float4 v = *(const float4*)(row + f);
    float s = v.x + v.y + v.z + v.w;
#pragma unroll
    for (int off = 32; off; off >>= 1) s += __shfl_down(s, off);
    float mu = __shfl(s, 0) * (1.f / 256.f);
    float dx = v.x - mu, dy = v.y - mu, dz = v.z - mu, dw = v.w - mu;
    float q = dx * dx + dy * dy + dz * dz + dw * dw;
#pragma unroll
    for (int off = 32; off; off >>= 1) q += __shfl_down(q, off);
    float var = __shfl(q, 0) * (1.f / 256.f);
    float r = rsqrtf(var + 1e-5f);
    float4 ov;
    ov.x = dx * r * g[f + 0] + b[f + 0];
    ov.y = dy * r * g[f + 1] + b[f + 1];
    ov.z = dz * r * g[f + 2] + b[f + 2];
    ov.w = dw * r * g[f + 3] + b[f + 3];
    *(float4*)(x + ((long long)n * TLEN + t) * FEAT + f) = ov;
}

// ---------------------------------------------------------------------------
// Masked mean-pool + output projection (x2 outputs). valid_cxr is int32.
// ---------------------------------------------------------------------------
__global__ __launch_bounds__(1024) void pool_out_kernel(
    const float* __restrict__ x, const float* __restrict__ W,
    const float* __restrict__ b, const int* __restrict__ seqlen,
    const int* __restrict__ valid_cxr, float* __restrict__ out)
{
    int n = blockIdx.x;
    int tid = threadIdx.x;
    int f = tid & 255;
    int tg = tid >> 8;
    int cnt = (n & 1) ? (valid_cxr[n >> 1] != 0 ? 1 : 0) : seqlen[n >> 1];

    __shared__ float part[4][FEAT];
    __shared__ float pooled[FEAT];

    const float* xb = x + (long long)n * TLEN * FEAT + f;
    float s0 = 0.f, s1 = 0.f;
    int t = tg;
    for (; t + 4 < cnt; t += 8) {
        s0 += xb[(long long)t * FEAT];
        s1 += xb[(long long)(t + 4) * FEAT];
    }
    if (t < cnt) s0 += xb[(long long)t * FEAT];
    part[tg][f] = s0 + s1;
    __syncthreads();
    if (tg == 0) {
        float v = part[0][f] + part[1][f] + part[2][f] + part[3][f];
        pooled[f] = cnt ? v / (float)cnt : 0.f;
    }
    __syncthreads();

    float acc = 0.f;
    const float* wcol = W + f;
#pragma unroll 8
    for (int k = tg * 64; k < tg * 64 + 64; ++k)
        acc += pooled[k] * wcol[(long long)k * FEAT];
    __syncthreads();
    part[tg][f] = acc;
    __syncthreads();
    if (tg == 0) {
        float v = part[0][f] + part[1][f] + part[2][f] + part[3][f] + b[f];
        out[(long long)n * FEAT + f] = v;
        out[NROWS * FEAT + (long long)n * FEAT + f] = v;
    }
}

// ---------------------------------------------------------------------------
extern "C" void kernel_launch(void* const* d_in, const int* in_sizes, int n_in,
                              void* d_out, int out_size, void* d_ws, size_t ws_size,
                              hipStream_t stream)
{
    const float* ehr_data = (const float*)d_in[0];
    const float* cxr_data = (const float*)d_in[1];
    const int*   seqlen   = (const int*)d_in[2];
    const int*   valid_cxr = (const int*)d_in[3];
    const float* ehr_w = (const float*)d_in[4];
    const float* ehr_b = (const float*)d_in[5];
    const float* cxr_w = (const float*)d_in[6];
    const float* cxr_b = (const float*)d_in[7];
    const float* modemb = (const float*)d_in[8];
    const float* pos    = (const float*)d_in[9];
    const float* qkv_w  = (const float*)d_in[10];
    const float* qkv_b  = (const float*)d_in[11];
    const float* aow    = (const float*)d_in[12];
    const float* aob    = (const float*)d_in[13];
    const float* ln1g   = (const float*)d_in[14];
    const float* ln1b   = (const float*)d_in[15];
    const float* ln2g   = (const float*)d_in[16];
    const float* ln2b   = (const float*)d_in[17];
    const float* ff1w   = (const float*)d_in[18];
    const float* ff1b   = (const float*)d_in[19];
    const float* ff2w   = (const float*)d_in[20];
    const float* ff2b   = (const float*)d_in[21];
    const float* outw   = (const float*)d_in[22];
    const float* outb   = (const float*)d_in[23];
    float* out = (float*)d_out;

    float* ws   = (float*)d_ws;
    float* x    = ws;                  // 32*501*256
    float* qkv  = ws + 4104192;        // 32*501*768
    float* obuf = ws + 16416768;       // 32*501*256
    float* tmp  = ws + 20520960;       // 32*501*256
    float* h    = qkv;                 // overlays qkv+obuf
    __bf16* wb  = (__bf16*)(ws + 24625152);  // bf16 W^T pool (~6 MB)

    WPack p;
    unsigned off = 0;
    p.d[0] = { ehr_w, off, EHR_IN, FEAT, 512 };            off += 256 * 512;
    unsigned qkvOff = off;
    for (int l = 0; l < 3; ++l) { p.d[1 + l] = { qkv_w + (long long)l * FEAT * 768, off, FEAT, 768, FEAT };  off += 768 * FEAT; }
    unsigned aoOff = off;
    for (int l = 0; l < 3; ++l) { p.d[4 + l] = { aow + (long long)l * FEAT * FEAT, off, FEAT, FEAT, FEAT };  off += FEAT * FEAT; }
    unsigned ff1Off = off;
    for (int l = 0; l < 3; ++l) { p.d[7 + l] = { ff1w + (long long)l * FEAT * FFDIM, off, FEAT, FFDIM, FEAT }; off += FFDIM * FEAT; }
    unsigned ff2Off = off;
    for (int l = 0; l < 3; ++l) { p.d[10 + l] = { ff2w + (long long)l * FFDIM * FEAT, off, FFDIM, FEAT, FFDIM }; off += FEAT * FFDIM; }
    unsigned cxrOff = off;
    p.d[13] = { cxr_w, off, CXR_IN, FEAT, CXR_IN };        off += FEAT * CXR_IN;

    wconv_kernel<<<dim3(32, 64, 14), 256, 0, stream>>>(p, wb);

    gemm_mfma<<<dim3(8, 4, 16), 256, 0, stream>>>(
        ehr_data, EHR_IN, (long long)MAXLEN * EHR_IN, MAXLEN,
        wb + 0, 512, EHR_IN,
        x, FEAT, (long long)2 * TLEN * FEAT,
        ehr_b, nullptr, 0, modemb, pos, seqlen, 0, F_POSEMB);
    gemm_mfma<<<dim3(1, 4, 1), 256, 0, stream>>>(
        cxr_data, CXR_IN, 0, BATCH,
        wb + cxrOff, CXR_IN, CXR_IN,
        x + (long long)TLEN * FEAT, 2 * TLEN * FEAT, 0,
        cxr_b, nullptr, 0, modemb + FEAT, pos, seqlen, 2, F_POS0);

    for (int l = 0; l < NLAYERS; ++l) {
        gemm_mfma<<<dim3(8, 12, 32), 256, 0, stream>>>(
            x, FEAT, (long long)TLEN * FEAT, TLEN,
            wb + qkvOff + (long long)l * 768 * FEAT, FEAT, FEAT,
            qkv, 3 * FEAT, (long long)TLEN * 3 * FEAT,
            qkv_b + (long long)l * 3 * FEAT, nullptr, 0, nullptr, nullptr, seqlen, 1, 0);

        attn_mfma<<<dim3(8, NHEAD, NROWS), 256, 0, stream>>>(qkv, obuf, seqlen);

        gemm_mfma<<<dim3(8, 4, 32), 256, 0, stream>>>(
            obuf, FEAT, (long long)TLEN * FEAT, TLEN,
            wb + aoOff + (long long)l * FEAT * FEAT, FEAT, FEAT,
            tmp, FEAT, (long long)TLEN * FEAT,
            aob + (long long)l * FEAT, x, (long long)TLEN * FEAT, nullptr, nullptr, seqlen, 1, F_RESID);

        ln_kernel<<<dim3(TLEN, NROWS), 64, 0, stream>>>(
            tmp, x, ln1g + l * FEAT, ln1b + l * FEAT, seqlen);

        gemm_mfma<<<dim3(8, 16, 32), 256, 0, stream>>>(
            x, FEAT, (long long)TLEN * FEAT, TLEN,
            wb + ff1Off + (long long)l * FFDIM * FEAT, FEAT, FEAT,
            h, FFDIM, (long long)TLEN * FFDIM,
            ff1b + (long long)l * FFDIM, nullptr, 0, nullptr, nullptr, seqlen, 1, F_GELU);

        gemm_mfma<<<dim3(8, 4, 32), 256, 0, stream>>>(
            h, FFDIM, (long long)TLEN * FFDIM, TLEN,
            wb + ff2Off + (long long)l * FEAT * FFDIM, FFDIM, FFDIM,
            tmp, FEAT, (long long)TLEN * FEAT,
            ff2b + (long long)l * FEAT, x, (long long)TLEN * FEAT, nullptr, nullptr, seqlen, 1, F_RESID);

        ln_kernel<<<dim3(TLEN, NROWS), 64, 0, stream>>>(
            tmp, x, ln2g + l * FEAT, ln2b + l * FEAT, seqlen);
    }

    pool_out_kernel<<<NROWS, 1024, 0, stream>>>(x, outw, outb, seqlen, valid_cxr, out);
}

// Round 8
// 512.687 us; speedup vs baseline: 3.5815x; 1.0823x over previous
//
#include <hip/hip_runtime.h>
#include <math.h>

#define FEAT 256
#define NHEAD 8
#define HD 32
#define NLAYERS 3
#define EHR_IN 498
#define MAXLEN 500
#define BATCH 16
#define CXR_IN 2048
#define FFDIM 1024
#define NROWS 32
#define TLEN 501

#define F_GELU 1
#define F_RESID 2
#define F_POSEMB 4
#define F_POS0 8

typedef __bf16 bf16x8 __attribute__((ext_vector_type(8)));
typedef __bf16 bf16x4 __attribute__((ext_vector_type(4)));
typedef float f32x4 __attribute__((ext_vector_type(4)));

// ---------------------------------------------------------------------------
// Weight prep: fp32 W[K][N] -> bf16 W^T[N][Kpad] (zero-padded K).
// ---------------------------------------------------------------------------
struct WDesc { const float* src; unsigned dstOff; int K, N, Kpad; };
struct WPack { WDesc d[13]; };

__global__ __launch_bounds__(256) void wconv_kernel(WPack p, __bf16* __restrict__ wb)
{
    WDesc w = p.d[blockIdx.z];
    int n0 = blockIdx.x * 32, k0 = blockIdx.y * 32;
    if (n0 >= w.N || k0 >= w.Kpad) return;
    __shared__ float t[32][33];
    int tid = threadIdx.x;
    int c = tid & 31, r = tid >> 5;
#pragma unroll
    for (int i = 0; i < 4; ++i) {
        int k = k0 + r + i * 8;
        int n = n0 + c;
        t[r + i * 8][c] = (k < w.K && n < w.N) ? w.src[(long long)k * w.N + n] : 0.f;
    }
    __syncthreads();
    int nl = tid >> 3, kq = (tid & 7) * 4;
    int n = n0 + nl;
    if (n < w.N) {
        bf16x4 v;
#pragma unroll
        for (int j = 0; j < 4; ++j) v[j] = (__bf16)t[kq + j][nl];
        *(bf16x4*)(wb + w.dstOff + (long long)n * w.Kpad + k0 + kq) = v;
    }
}

// ---------------------------------------------------------------------------
// bf16 MFMA GEMM (validated round 4). Tile 64x64, BK=32, 4 waves 2x2 frags.
// ---------------------------------------------------------------------------
__global__ __launch_bounds__(256) void gemm_mfma(
    const float* __restrict__ A, int lda, long long aStrideZ, int Mrows,
    const __bf16* __restrict__ WT, int kpad, int K,
    float* __restrict__ C, int ldc, long long cStrideZ,
    const float* __restrict__ bias,
    const float* __restrict__ resid, long long resStrideZ,
    const float* __restrict__ modv, const float* __restrict__ posm,
    const int* __restrict__ seqlen, int lenMode, int flags)
{
    int z = blockIdx.z;
    int len = (lenMode == 2) ? Mrows
            : (lenMode == 0) ? seqlen[z]
            : ((z & 1) ? 1 : seqlen[z >> 1]);
    int m0 = blockIdx.x * 64;
    if (m0 >= len) return;
    int n0 = blockIdx.y * 64;

    const float* Az = A + (long long)z * aStrideZ;
    float* Cz = C + (long long)z * cStrideZ;

    __shared__ __bf16 As[64][40];
    __shared__ __bf16 Bs[64][40];

    int tid = threadIdx.x;
    int wave = tid >> 6, lane = tid & 63;
    int wm = wave >> 1, wn = wave & 1;
    int fm = lane & 15, kgrp = lane >> 4;

    f32x4 acc[2][2];
#pragma unroll
    for (int i = 0; i < 2; ++i)
#pragma unroll
        for (int j = 0; j < 2; ++j)
#pragma unroll
            for (int r = 0; r < 4; ++r) acc[i][j][r] = 0.f;

    int srow = tid >> 2;
    int skq  = (tid & 3) * 8;
    int garow = m0 + srow;
    bool rowok = garow < Mrows;
    bool a16 = ((lda & 3) == 0);

    int nk = (K + 31) >> 5;
    for (int kt = 0; kt < nk; ++kt) {
        int k0 = kt << 5;
        float va[8];
        const float* ap = Az + (long long)garow * lda + k0 + skq;
        if (rowok && a16 && k0 + skq + 7 < K) {
            float4 t0 = *(const float4*)(ap);
            float4 t1 = *(const float4*)(ap + 4);
            va[0] = t0.x; va[1] = t0.y; va[2] = t0.z; va[3] = t0.w;
            va[4] = t1.x; va[5] = t1.y; va[6] = t1.z; va[7] = t1.w;
        } else if (rowok && !a16 && k0 + skq + 7 < K) {
#pragma unroll
            for (int j = 0; j < 8; j += 2) {
                float2 t = *(const float2*)(ap + j);
                va[j] = t.x; va[j + 1] = t.y;
            }
        } else {
#pragma unroll
            for (int j = 0; j < 8; ++j)
                va[j] = (rowok && k0 + skq + j < K) ? ap[j] : 0.f;
        }
        bf16x8 ab;
#pragma unroll
        for (int j = 0; j < 8; ++j) ab[j] = (__bf16)va[j];
        *(bf16x8*)&As[srow][skq] = ab;
        bf16x8 bb = *(const bf16x8*)(WT + (long long)(n0 + srow) * kpad + k0 + skq);
        *(bf16x8*)&Bs[srow][skq] = bb;

        __syncthreads();
        bf16x8 bfr[2];
#pragma unroll
        for (int j = 0; j < 2; ++j)
            bfr[j] = *(const bf16x8*)&Bs[wn * 32 + j * 16 + fm][kgrp * 8];
#pragma unroll
        for (int i = 0; i < 2; ++i) {
            bf16x8 af = *(const bf16x8*)&As[wm * 32 + i * 16 + fm][kgrp * 8];
#pragma unroll
            for (int j = 0; j < 2; ++j)
                acc[i][j] = __builtin_amdgcn_mfma_f32_16x16x32_bf16(af, bfr[j], acc[i][j], 0, 0, 0);
        }
        __syncthreads();
    }

    int rbase = (lane >> 4) * 4;
    int ccol = lane & 15;
#pragma unroll
    for (int i = 0; i < 2; ++i) {
#pragma unroll
        for (int r = 0; r < 4; ++r) {
            int gm = m0 + wm * 32 + i * 16 + rbase + r;
            if (gm >= len) continue;
#pragma unroll
            for (int j = 0; j < 2; ++j) {
                int gn = n0 + wn * 32 + j * 16 + ccol;
                float v = acc[i][j][r] + bias[gn];
                if (flags & F_POSEMB) v += modv[gn] + posm[(long long)gm * FEAT + gn];
                if (flags & F_POS0)   v += modv[gn] + posm[gn];
                if (flags & F_RESID)  v += resid[(long long)z * resStrideZ + (long long)gm * ldc + gn];
                if (flags & F_GELU)   v = 0.5f * v * (1.f + erff(v * 0.70710678118654752f));
                Cz[(long long)gm * ldc + gn] = v;
            }
        }
    }
}

// ---------------------------------------------------------------------------
// CXR projection, K-split 2-pass fp32 (replaces the 4-block MFMA call that
// was the #1 dispatch at 49 us: 16.8 MFLOP needs parallelism, not MFMA).
// Pass 1: grid (b, ks) = (16, 16); thread n accumulates a 128-k slice.
// ---------------------------------------------------------------------------
__global__ __launch_bounds__(256) void cxr_part(
    const float* __restrict__ cxr, const float* __restrict__ W,
    float* __restrict__ part)
{
    int b = blockIdx.x, ks = blockIdx.y;
    int n = threadIdx.x;
    __shared__ float a[128];
    int k0 = ks * 128;
    if (n < 128) a[n] = cxr[(long long)b * CXR_IN + k0 + n];
    __syncthreads();
    float acc0 = 0.f, acc1 = 0.f, acc2 = 0.f, acc3 = 0.f;
    const float* wp = W + (long long)k0 * FEAT + n;
#pragma unroll 8
    for (int k = 0; k < 128; k += 4) {
        acc0 += a[k]     * wp[(long long)k * FEAT];
        acc1 += a[k + 1] * wp[(long long)(k + 1) * FEAT];
        acc2 += a[k + 2] * wp[(long long)(k + 2) * FEAT];
        acc3 += a[k + 3] * wp[(long long)(k + 3) * FEAT];
    }
    part[((long long)b * 16 + ks) * FEAT + n] = acc0 + acc1 + acc2 + acc3;
}

// Pass 2: fold 16 partials + bias + modality emb + pos[0] -> x odd rows.
__global__ __launch_bounds__(256) void cxr_fin(
    const float* __restrict__ part, const float* __restrict__ bias,
    const float* __restrict__ mod1, const float* __restrict__ pos0,
    float* __restrict__ x)
{
    int b = blockIdx.x;
    int n = threadIdx.x;
    float s = 0.f;
#pragma unroll
    for (int ks = 0; ks < 16; ++ks)
        s += part[((long long)b * 16 + ks) * FEAT + n];
    x[((long long)(2 * b + 1) * TLEN) * FEAT + n] = s + bias[n] + mod1[n] + pos0[n];
}

// ---------------------------------------------------------------------------
// MFMA flash attention (validated round 6): 64-key tiles, permuted K-frag
// key order -> zero P-redistribution shuffles; pad-17 frag-linear LDS.
// ---------------------------------------------------------------------------
__global__ __launch_bounds__(256) void attn_mfma(
    const float* __restrict__ qkv, float* __restrict__ o,
    const int* __restrict__ seqlen)
{
    int n = blockIdx.z, h = blockIdx.y, qt = blockIdx.x;
    int len = (n & 1) ? 1 : seqlen[n >> 1];
    int q0 = qt * 64;
    if (q0 >= len) return;

    int tid = threadIdx.x;
    int wave = tid >> 6, lane = tid & 63;
    int fr = lane & 15, kg = lane >> 4;

    const float* base = qkv + (long long)n * TLEN * 768;
    const float scale = 0.17677669529663687f;

    int qrow = q0 + wave * 16 + fr;
    if (qrow >= len) qrow = len - 1;
    bf16x8 qfrag;
    {
        const float* qp = base + (long long)qrow * 768 + h * HD + kg * 8;
        float4 t0 = *(const float4*)(qp);
        float4 t1 = *(const float4*)(qp + 4);
        qfrag[0] = (__bf16)t0.x; qfrag[1] = (__bf16)t0.y;
        qfrag[2] = (__bf16)t0.z; qfrag[3] = (__bf16)t0.w;
        qfrag[4] = (__bf16)t1.x; qfrag[5] = (__bf16)t1.y;
        qfrag[6] = (__bf16)t1.z; qfrag[7] = (__bf16)t1.w;
    }

    f32x4 po0 = {0.f, 0.f, 0.f, 0.f}, po1 = {0.f, 0.f, 0.f, 0.f};
    float m = -3.0e38f, l = 0.f;

    __shared__ bf16x8 stage[2][544];

    int f_    = tid >> 6;
    int kgrp_ = (tid >> 4) & 3;
    int mm_   = tid & 15;
    int kKeyL  = ((mm_ >> 2) << 3) + ((f_ & 1) << 2) + (mm_ & 3) + ((f_ >> 1) << 5);
    int kChunk = (f_ * 4 + kgrp_) * 17 + mm_;
    int vDim   = ((f_ & 1) << 4) + mm_;
    int vKeyB  = ((f_ >> 1) << 5) + (kgrp_ << 3);
    int vChunk = 272 + (f_ * 4 + kgrp_) * 17 + mm_;

    int nt = (len + 63) >> 6;

    auto do_stage = [&](int t, int buf) {
        int k0 = t << 6;
        bf16x8 kv;
        int key = k0 + kKeyL;
        if (key < len) {
            const float* kp = base + (long long)key * 768 + 256 + h * HD + kgrp_ * 8;
            float4 t0 = *(const float4*)(kp);
            float4 t1 = *(const float4*)(kp + 4);
            kv[0] = (__bf16)t0.x; kv[1] = (__bf16)t0.y; kv[2] = (__bf16)t0.z; kv[3] = (__bf16)t0.w;
            kv[4] = (__bf16)t1.x; kv[5] = (__bf16)t1.y; kv[6] = (__bf16)t1.z; kv[7] = (__bf16)t1.w;
        } else {
#pragma unroll
            for (int j = 0; j < 8; ++j) kv[j] = (__bf16)0.f;
        }
        stage[buf][kChunk] = kv;
        bf16x8 vv;
#pragma unroll
        for (int j = 0; j < 8; ++j) {
            int vkey = k0 + vKeyB + j;
            vv[j] = (vkey < len) ? (__bf16)base[(long long)vkey * 768 + 512 + h * HD + vDim]
                                 : (__bf16)0.f;
        }
        stage[buf][vChunk] = vv;
    };

    do_stage(0, 0);
    __syncthreads();

    for (int t = 0; t < nt; ++t) {
        int buf = t & 1;
        if (t + 1 < nt) do_stage(t + 1, buf ^ 1);

        int k0 = t << 6;
        bf16x8 kf0 = stage[buf][(0 * 4 + kg) * 17 + fr];
        bf16x8 kf1 = stage[buf][(1 * 4 + kg) * 17 + fr];
        bf16x8 kf2 = stage[buf][(2 * 4 + kg) * 17 + fr];
        bf16x8 kf3 = stage[buf][(3 * 4 + kg) * 17 + fr];

        f32x4 zero = {0.f, 0.f, 0.f, 0.f};
        f32x4 s0 = __builtin_amdgcn_mfma_f32_16x16x32_bf16(kf0, qfrag, zero, 0, 0, 0);
        f32x4 s1 = __builtin_amdgcn_mfma_f32_16x16x32_bf16(kf1, qfrag, zero, 0, 0, 0);
        f32x4 s2 = __builtin_amdgcn_mfma_f32_16x16x32_bf16(kf2, qfrag, zero, 0, 0, 0);
        f32x4 s3 = __builtin_amdgcn_mfma_f32_16x16x32_bf16(kf3, qfrag, zero, 0, 0, 0);

        float sc[16];
        int kb = k0 + kg * 8;
#pragma unroll
        for (int r = 0; r < 4; ++r) {
            sc[r]      = (kb + r < len)      ? s0[r] * scale : -3.0e38f;
            sc[4 + r]  = (kb + 4 + r < len)  ? s1[r] * scale : -3.0e38f;
            sc[8 + r]  = (kb + 32 + r < len) ? s2[r] * scale : -3.0e38f;
            sc[12 + r] = (kb + 36 + r < len) ? s3[r] * scale : -3.0e38f;
        }
        float tm = sc[0];
#pragma unroll
        for (int i = 1; i < 16; ++i) tm = fmaxf(tm, sc[i]);
        tm = fmaxf(tm, __shfl_xor(tm, 16));
        tm = fmaxf(tm, __shfl_xor(tm, 32));
        float mn = fmaxf(m, tm);
        float corr = __expf(m - mn);
        l *= corr;
#pragma unroll
        for (int r = 0; r < 4; ++r) { po0[r] *= corr; po1[r] *= corr; }
        m = mn;

        float p[16];
        float lsum = 0.f;
#pragma unroll
        for (int i = 0; i < 16; ++i) { p[i] = __expf(sc[i] - m); lsum += p[i]; }
        lsum += __shfl_xor(lsum, 16);
        lsum += __shfl_xor(lsum, 32);
        l += lsum;

        bf16x8 pf0, pf1;
#pragma unroll
        for (int j = 0; j < 8; ++j) { pf0[j] = (__bf16)p[j]; pf1[j] = (__bf16)p[8 + j]; }

        bf16x8 vf00 = stage[buf][272 + (0 * 4 + kg) * 17 + fr];
        bf16x8 vf01 = stage[buf][272 + (1 * 4 + kg) * 17 + fr];
        bf16x8 vf10 = stage[buf][272 + (2 * 4 + kg) * 17 + fr];
        bf16x8 vf11 = stage[buf][272 + (3 * 4 + kg) * 17 + fr];

        po0 = __builtin_amdgcn_mfma_f32_16x16x32_bf16(vf00, pf0, po0, 0, 0, 0);
        po0 = __builtin_amdgcn_mfma_f32_16x16x32_bf16(vf10, pf1, po0, 0, 0, 0);
        po1 = __builtin_amdgcn_mfma_f32_16x16x32_bf16(vf01, pf0, po1, 0, 0, 0);
        po1 = __builtin_amdgcn_mfma_f32_16x16x32_bf16(vf11, pf1, po1, 0, 0, 0);

        __syncthreads();
    }

    int q = q0 + wave * 16 + fr;
    if (q < len) {
        float inv = 1.f / l;
        float* orow = o + ((long long)n * TLEN + q) * FEAT + h * HD;
        float4 w0, w1;
        w0.x = po0[0] * inv; w0.y = po0[1] * inv; w0.z = po0[2] * inv; w0.w = po0[3] * inv;
        w1.x = po1[0] * inv; w1.y = po1[1] * inv; w1.z = po1[2] * inv; w1.w = po1[3] * inv;
        *(float4*)(orow + kg * 4) = w0;
        *(float4*)(orow + 16 + kg * 4) = w1;
    }
}

// ---------------------------------------------------------------------------
// LayerNorm over last dim (256), one wave per valid token row.
// ---------------------------------------------------------------------------
__global__ __launch_bounds__(64) void ln_kernel(
    const float* __restrict__ tmp, float* __restrict__ x,
    const float* __restrict__ g, const float* __restrict__ b,
    const int* __restrict__ seqlen)
{
    int t = blockIdx.x, n = blockIdx.y;
    int len = (n & 1) ? 1 : seqlen[n >> 1];
    if (t >= len) return;
    int tid = threadIdx.x;
    const float* row = tmp + ((long long)n * TLEN + t) * FEAT;
    int f = tid * 4;
    float4 v = *(const float4*)(row + f);
    float s = v.x + v.y + v.z + v.w;
#pragma unroll
    for (int off = 32; off; off >>= 1) s += __shfl_down(s, off);
    float mu = __shfl(s, 0) * (1.f / 256.f);
    float dx = v.x - mu, dy = v.y - mu, dz = v.z - mu, dw = v.w - mu;
    float q = dx * dx + dy * dy + dz * dz + dw * dw;
#pragma unroll
    for (int off = 32; off; off >>= 1) q += __shfl_down(q, off);
    float var = __shfl(q, 0) * (1.f / 256.f);
    float r = rsqrtf(var + 1e-5f);
    float4 ov;
    ov.x = dx * r * g[f + 0] + b[f + 0];
    ov.y = dy * r * g[f + 1] + b[f + 1];
    ov.z = dz * r * g[f + 2] + b[f + 2];
    ov.w = dw * r * g[f + 3] + b[f + 3];
    *(float4*)(x + ((long long)n * TLEN + t) * FEAT + f) = ov;
}

// ---------------------------------------------------------------------------
// Masked mean-pool + output projection (x2 outputs). valid_cxr is int32.
// ---------------------------------------------------------------------------
__global__ __launch_bounds__(1024) void pool_out_kernel(
    const float* __restrict__ x, const float* __restrict__ W,
    const float* __restrict__ b, const int* __restrict__ seqlen,
    const int* __restrict__ valid_cxr, float* __restrict__ out)
{
    int n = blockIdx.x;
    int tid = threadIdx.x;
    int f = tid & 255;
    int tg = tid >> 8;
    int cnt = (n & 1) ? (valid_cxr[n >> 1] != 0 ? 1 : 0) : seqlen[n >> 1];

    __shared__ float part[4][FEAT];
    __shared__ float pooled[FEAT];

    const float* xb = x + (long long)n * TLEN * FEAT + f;
    float s0 = 0.f, s1 = 0.f;
    int t = tg;
    for (; t + 4 < cnt; t += 8) {
        s0 += xb[(long long)t * FEAT];
        s1 += xb[(long long)(t + 4) * FEAT];
    }
    if (t < cnt) s0 += xb[(long long)t * FEAT];
    part[tg][f] = s0 + s1;
    __syncthreads();
    if (tg == 0) {
        float v = part[0][f] + part[1][f] + part[2][f] + part[3][f];
        pooled[f] = cnt ? v / (float)cnt : 0.f;
    }
    __syncthreads();

    float acc = 0.f;
    const float* wcol = W + f;
#pragma unroll 8
    for (int k = tg * 64; k < tg * 64 + 64; ++k)
        acc += pooled[k] * wcol[(long long)k * FEAT];
    __syncthreads();
    part[tg][f] = acc;
    __syncthreads();
    if (tg == 0) {
        float v = part[0][f] + part[1][f] + part[2][f] + part[3][f] + b[f];
        out[(long long)n * FEAT + f] = v;
        out[NROWS * FEAT + (long long)n * FEAT + f] = v;
    }
}

// ---------------------------------------------------------------------------
extern "C" void kernel_launch(void* const* d_in, const int* in_sizes, int n_in,
                              void* d_out, int out_size, void* d_ws, size_t ws_size,
                              hipStream_t stream)
{
    const float* ehr_data = (const float*)d_in[0];
    const float* cxr_data = (const float*)d_in[1];
    const int*   seqlen   = (const int*)d_in[2];
    const int*   valid_cxr = (const int*)d_in[3];
    const float* ehr_w = (const float*)d_in[4];
    const float* ehr_b = (const float*)d_in[5];
    const float* cxr_w = (const float*)d_in[6];
    const float* cxr_b = (const float*)d_in[7];
    const float* modemb = (const float*)d_in[8];
    const float* pos    = (const float*)d_in[9];
    const float* qkv_w  = (const float*)d_in[10];
    const float* qkv_b  = (const float*)d_in[11];
    const float* aow    = (const float*)d_in[12];
    const float* aob    = (const float*)d_in[13];
    const float* ln1g   = (const float*)d_in[14];
    const float* ln1b   = (const float*)d_in[15];
    const float* ln2g   = (const float*)d_in[16];
    const float* ln2b   = (const float*)d_in[17];
    const float* ff1w   = (const float*)d_in[18];
    const float* ff1b   = (const float*)d_in[19];
    const float* ff2w   = (const float*)d_in[20];
    const float* ff2b   = (const float*)d_in[21];
    const float* outw   = (const float*)d_in[22];
    const float* outb   = (const float*)d_in[23];
    float* out = (float*)d_out;

    float* ws   = (float*)d_ws;
    float* x    = ws;                  // 32*501*256
    float* qkv  = ws + 4104192;        // 32*501*768
    float* obuf = ws + 16416768;       // 32*501*256
    float* tmp  = ws + 20520960;       // 32*501*256
    float* h    = qkv;                 // overlays qkv+obuf
    __bf16* wb  = (__bf16*)(ws + 24625152);  // bf16 W^T pool (~5 MB)
    float* cpart = ws + 24625152 + 1245184; // 16x16x256 fp32 partials (256 KB)

    WPack p;
    unsigned off = 0;
    p.d[0] = { ehr_w, off, EHR_IN, FEAT, 512 };            off += 256 * 512;
    unsigned qkvOff = off;
    for (int l = 0; l < 3; ++l) { p.d[1 + l] = { qkv_w + (long long)l * FEAT * 768, off, FEAT, 768, FEAT };  off += 768 * FEAT; }
    unsigned aoOff = off;
    for (int l = 0; l < 3; ++l) { p.d[4 + l] = { aow + (long long)l * FEAT * FEAT, off, FEAT, FEAT, FEAT };  off += FEAT * FEAT; }
    unsigned ff1Off = off;
    for (int l = 0; l < 3; ++l) { p.d[7 + l] = { ff1w + (long long)l * FEAT * FFDIM, off, FEAT, FFDIM, FEAT }; off += FFDIM * FEAT; }
    unsigned ff2Off = off;
    for (int l = 0; l < 3; ++l) { p.d[10 + l] = { ff2w + (long long)l * FFDIM * FEAT, off, FFDIM, FEAT, FFDIM }; off += FEAT * FFDIM; }

    wconv_kernel<<<dim3(32, 32, 13), 256, 0, stream>>>(p, wb);

    // ehr projection -> even rows of x
    gemm_mfma<<<dim3(8, 4, 16), 256, 0, stream>>>(
        ehr_data, EHR_IN, (long long)MAXLEN * EHR_IN, MAXLEN,
        wb + 0, 512, EHR_IN,
        x, FEAT, (long long)2 * TLEN * FEAT,
        ehr_b, nullptr, 0, modemb, pos, seqlen, 0, F_POSEMB);
    // cxr projection -> odd rows token 0 (K-split 2-pass fp32)
    cxr_part<<<dim3(BATCH, 16), 256, 0, stream>>>(cxr_data, cxr_w, cpart);
    cxr_fin<<<BATCH, 256, 0, stream>>>(cpart, cxr_b, modemb + FEAT, pos, x);

    for (int l = 0; l < NLAYERS; ++l) {
        gemm_mfma<<<dim3(8, 12, 32), 256, 0, stream>>>(
            x, FEAT, (long long)TLEN * FEAT, TLEN,
            wb + qkvOff + (long long)l * 768 * FEAT, FEAT, FEAT,
            qkv, 3 * FEAT, (long long)TLEN * 3 * FEAT,
            qkv_b + (long long)l * 3 * FEAT, nullptr, 0, nullptr, nullptr, seqlen, 1, 0);

        attn_mfma<<<dim3(8, NHEAD, NROWS), 256, 0, stream>>>(qkv, obuf, seqlen);

        gemm_mfma<<<dim3(8, 4, 32), 256, 0, stream>>>(
            obuf, FEAT, (long long)TLEN * FEAT, TLEN,
            wb + aoOff + (long long)l * FEAT * FEAT, FEAT, FEAT,
            tmp, FEAT, (long long)TLEN * FEAT,
            aob + (long long)l * FEAT, x, (long long)TLEN * FEAT, nullptr, nullptr, seqlen, 1, F_RESID);

        ln_kernel<<<dim3(TLEN, NROWS), 64, 0, stream>>>(
            tmp, x, ln1g + l * FEAT, ln1b + l * FEAT, seqlen);

        gemm_mfma<<<dim3(8, 16, 32), 256, 0, stream>>>(
            x, FEAT, (long long)TLEN * FEAT, TLEN,
            wb + ff1Off + (long long)l * FFDIM * FEAT, FEAT, FEAT,
            h, FFDIM, (long long)TLEN * FFDIM,
            ff1b + (long long)l * FFDIM, nullptr, 0, nullptr, nullptr, seqlen, 1, F_GELU);

        gemm_mfma<<<dim3(8, 4, 32), 256, 0, stream>>>(
            h, FFDIM, (long long)TLEN * FFDIM, TLEN,
            wb + ff2Off + (long long)l * FEAT * FFDIM, FFDIM, FFDIM,
            tmp, FEAT, (long long)TLEN * FEAT,
            ff2b + (long long)l * FEAT, x, (long long)TLEN * FEAT, nullptr, nullptr, seqlen, 1, F_RESID);

        ln_kernel<<<dim3(TLEN, NROWS), 64, 0, stream>>>(
            tmp, x, ln2g + l * FEAT, ln2b + l * FEAT, seqlen);
    }

    pool_out_kernel<<<NROWS, 1024, 0, stream>>>(x, outw, outb, seqlen, valid_cxr, out);
}

// Round 9
// 466.059 us; speedup vs baseline: 3.9398x; 1.1000x over previous
//
#include <hip/hip_runtime.h>
#include <math.h>

#define FEAT 256
#define NHEAD 8
#define HD 32
#define NLAYERS 3
#define EHR_IN 498
#define MAXLEN 500
#define BATCH 16
#define CXR_IN 2048
#define FFDIM 1024
#define NROWS 32
#define TLEN 501

#define F_GELU 1
#define F_RESID 2
#define F_POSEMB 4
#define F_POS0 8

typedef __bf16 bf16x8 __attribute__((ext_vector_type(8)));
typedef __bf16 bf16x4 __attribute__((ext_vector_type(4)));
typedef float f32x4 __attribute__((ext_vector_type(4)));

// ---------------------------------------------------------------------------
// Weight prep: fp32 W[K][N] -> bf16 W^T[N][Kpad] (zero-padded K).
// ---------------------------------------------------------------------------
struct WDesc { const float* src; unsigned dstOff; int K, N, Kpad; };
struct WPack { WDesc d[13]; };

__global__ __launch_bounds__(256) void wconv_kernel(WPack p, __bf16* __restrict__ wb)
{
    WDesc w = p.d[blockIdx.z];
    int n0 = blockIdx.x * 32, k0 = blockIdx.y * 32;
    if (n0 >= w.N || k0 >= w.Kpad) return;
    __shared__ float t[32][33];
    int tid = threadIdx.x;
    int c = tid & 31, r = tid >> 5;
#pragma unroll
    for (int i = 0; i < 4; ++i) {
        int k = k0 + r + i * 8;
        int n = n0 + c;
        t[r + i * 8][c] = (k < w.K && n < w.N) ? w.src[(long long)k * w.N + n] : 0.f;
    }
    __syncthreads();
    int nl = tid >> 3, kq = (tid & 7) * 4;
    int n = n0 + nl;
    if (n < w.N) {
        bf16x4 v;
#pragma unroll
        for (int j = 0; j < 4; ++j) v[j] = (__bf16)t[kq + j][nl];
        *(bf16x4*)(wb + w.dstOff + (long long)n * w.Kpad + k0 + kq) = v;
    }
}

// ---------------------------------------------------------------------------
// bf16 MFMA GEMM, templated on A/C dtypes (ABF/CBF: 1 = bf16, 0 = fp32).
// bf16 intermediates are provably error-free: consumers converted to bf16
// anyway, so rounding at the producer store is bit-identical.
// Tile 64x64, BK=32, 4 waves of 2x2 16x16x32 fragments (validated round 4).
// ---------------------------------------------------------------------------
template<int ABF, int CBF>
__global__ __launch_bounds__(256) void gemm_mfma(
    const void* __restrict__ Av, int lda, long long aStrideZ, int Mrows,
    const __bf16* __restrict__ WT, int kpad, int K,
    void* __restrict__ Cv, int ldc, long long cStrideZ,
    const float* __restrict__ bias,
    const float* __restrict__ resid, long long resStrideZ,
    const float* __restrict__ modv, const float* __restrict__ posm,
    const int* __restrict__ seqlen, int lenMode, int flags)
{
    int z = blockIdx.z;
    int len = (lenMode == 2) ? Mrows
            : (lenMode == 0) ? seqlen[z]
            : ((z & 1) ? 1 : seqlen[z >> 1]);
    int m0 = blockIdx.x * 64;
    if (m0 >= len) return;
    int n0 = blockIdx.y * 64;

    __shared__ __bf16 As[64][40];
    __shared__ __bf16 Bs[64][40];

    int tid = threadIdx.x;
    int wave = tid >> 6, lane = tid & 63;
    int wm = wave >> 1, wn = wave & 1;
    int fm = lane & 15, kgrp = lane >> 4;

    f32x4 acc[2][2];
#pragma unroll
    for (int i = 0; i < 2; ++i)
#pragma unroll
        for (int j = 0; j < 2; ++j)
#pragma unroll
            for (int r = 0; r < 4; ++r) acc[i][j][r] = 0.f;

    int srow = tid >> 2;
    int skq  = (tid & 3) * 8;
    int garow = m0 + srow;
    bool rowok = garow < Mrows;

    int nk = (K + 31) >> 5;
    for (int kt = 0; kt < nk; ++kt) {
        int k0 = kt << 5;
        bf16x8 ab;
        if (ABF) {
            // bf16 A: K is always a multiple of 32 here; pure vector copy.
            if (rowok) {
                const __bf16* ap = (const __bf16*)Av + (long long)z * aStrideZ
                                 + (long long)garow * lda + k0 + skq;
                ab = *(const bf16x8*)ap;
            } else {
#pragma unroll
                for (int j = 0; j < 8; ++j) ab[j] = (__bf16)0.f;
            }
        } else {
            const float* Az = (const float*)Av + (long long)z * aStrideZ;
            float va[8];
            const float* ap = Az + (long long)garow * lda + k0 + skq;
            bool a16 = ((lda & 3) == 0);
            if (rowok && a16 && k0 + skq + 7 < K) {
                float4 t0 = *(const float4*)(ap);
                float4 t1 = *(const float4*)(ap + 4);
                va[0] = t0.x; va[1] = t0.y; va[2] = t0.z; va[3] = t0.w;
                va[4] = t1.x; va[5] = t1.y; va[6] = t1.z; va[7] = t1.w;
            } else if (rowok && !a16 && k0 + skq + 7 < K) {
#pragma unroll
                for (int j = 0; j < 8; j += 2) {
                    float2 t = *(const float2*)(ap + j);
                    va[j] = t.x; va[j + 1] = t.y;
                }
            } else {
#pragma unroll
                for (int j = 0; j < 8; ++j)
                    va[j] = (rowok && k0 + skq + j < K) ? ap[j] : 0.f;
            }
#pragma unroll
            for (int j = 0; j < 8; ++j) ab[j] = (__bf16)va[j];
        }
        *(bf16x8*)&As[srow][skq] = ab;
        bf16x8 bb = *(const bf16x8*)(WT + (long long)(n0 + srow) * kpad + k0 + skq);
        *(bf16x8*)&Bs[srow][skq] = bb;

        __syncthreads();
        bf16x8 bfr[2];
#pragma unroll
        for (int j = 0; j < 2; ++j)
            bfr[j] = *(const bf16x8*)&Bs[wn * 32 + j * 16 + fm][kgrp * 8];
#pragma unroll
        for (int i = 0; i < 2; ++i) {
            bf16x8 af = *(const bf16x8*)&As[wm * 32 + i * 16 + fm][kgrp * 8];
#pragma unroll
            for (int j = 0; j < 2; ++j)
                acc[i][j] = __builtin_amdgcn_mfma_f32_16x16x32_bf16(af, bfr[j], acc[i][j], 0, 0, 0);
        }
        __syncthreads();
    }

    int rbase = (lane >> 4) * 4;
    int ccol = lane & 15;
#pragma unroll
    for (int i = 0; i < 2; ++i) {
#pragma unroll
        for (int r = 0; r < 4; ++r) {
            int gm = m0 + wm * 32 + i * 16 + rbase + r;
            if (gm >= len) continue;
#pragma unroll
            for (int j = 0; j < 2; ++j) {
                int gn = n0 + wn * 32 + j * 16 + ccol;
                float v = acc[i][j][r] + bias[gn];
                if (flags & F_POSEMB) v += modv[gn] + posm[(long long)gm * FEAT + gn];
                if (flags & F_POS0)   v += modv[gn] + posm[gn];
                if (flags & F_RESID)  v += resid[(long long)z * resStrideZ + (long long)gm * ldc + gn];
                if (flags & F_GELU)   v = 0.5f * v * (1.f + erff(v * 0.70710678118654752f));
                long long cidx = (long long)z * cStrideZ + (long long)gm * ldc + gn;
                if (CBF) ((__bf16*)Cv)[cidx] = (__bf16)v;
                else     ((float*)Cv)[cidx] = v;
            }
        }
    }
}

// ---------------------------------------------------------------------------
// CXR projection, K-split 2-pass fp32 (validated round 7).
// ---------------------------------------------------------------------------
__global__ __launch_bounds__(256) void cxr_part(
    const float* __restrict__ cxr, const float* __restrict__ W,
    float* __restrict__ part)
{
    int b = blockIdx.x, ks = blockIdx.y;
    int n = threadIdx.x;
    __shared__ float a[128];
    int k0 = ks * 128;
    if (n < 128) a[n] = cxr[(long long)b * CXR_IN + k0 + n];
    __syncthreads();
    float acc0 = 0.f, acc1 = 0.f, acc2 = 0.f, acc3 = 0.f;
    const float* wp = W + (long long)k0 * FEAT + n;
#pragma unroll 8
    for (int k = 0; k < 128; k += 4) {
        acc0 += a[k]     * wp[(long long)k * FEAT];
        acc1 += a[k + 1] * wp[(long long)(k + 1) * FEAT];
        acc2 += a[k + 2] * wp[(long long)(k + 2) * FEAT];
        acc3 += a[k + 3] * wp[(long long)(k + 3) * FEAT];
    }
    part[((long long)b * 16 + ks) * FEAT + n] = acc0 + acc1 + acc2 + acc3;
}

__global__ __launch_bounds__(256) void cxr_fin(
    const float* __restrict__ part, const float* __restrict__ bias,
    const float* __restrict__ mod1, const float* __restrict__ pos0,
    float* __restrict__ x)
{
    int b = blockIdx.x;
    int n = threadIdx.x;
    float s = 0.f;
#pragma unroll
    for (int ks = 0; ks < 16; ++ks)
        s += part[((long long)b * 16 + ks) * FEAT + n];
    x[((long long)(2 * b + 1) * TLEN) * FEAT + n] = s + bias[n] + mod1[n] + pos0[n];
}

// ---------------------------------------------------------------------------
// MFMA flash attention on bf16 qkv (permuted K-frag key order -> zero
// P-redistribution shuffles; pad-17 frag-linear LDS; validated round 6).
// Output obuf is bf16 (consumer converts anyway).
// ---------------------------------------------------------------------------
__global__ __launch_bounds__(256) void attn_mfma(
    const __bf16* __restrict__ qkv, __bf16* __restrict__ o,
    const int* __restrict__ seqlen)
{
    int n = blockIdx.z, h = blockIdx.y, qt = blockIdx.x;
    int len = (n & 1) ? 1 : seqlen[n >> 1];
    int q0 = qt * 64;
    if (q0 >= len) return;

    int tid = threadIdx.x;
    int wave = tid >> 6, lane = tid & 63;
    int fr = lane & 15, kg = lane >> 4;

    const __bf16* base = qkv + (long long)n * TLEN * 768;
    const float scale = 0.17677669529663687f;

    int qrow = q0 + wave * 16 + fr;
    if (qrow >= len) qrow = len - 1;
    bf16x8 qfrag = *(const bf16x8*)(base + (long long)qrow * 768 + h * HD + kg * 8);

    f32x4 po0 = {0.f, 0.f, 0.f, 0.f}, po1 = {0.f, 0.f, 0.f, 0.f};
    float m = -3.0e38f, l = 0.f;

    __shared__ bf16x8 stage[2][544];

    int f_    = tid >> 6;
    int kgrp_ = (tid >> 4) & 3;
    int mm_   = tid & 15;
    int kKeyL  = ((mm_ >> 2) << 3) + ((f_ & 1) << 2) + (mm_ & 3) + ((f_ >> 1) << 5);
    int kChunk = (f_ * 4 + kgrp_) * 17 + mm_;
    int vDim   = ((f_ & 1) << 4) + mm_;
    int vKeyB  = ((f_ >> 1) << 5) + (kgrp_ << 3);
    int vChunk = 272 + (f_ * 4 + kgrp_) * 17 + mm_;

    int nt = (len + 63) >> 6;

    auto do_stage = [&](int t, int buf) {
        int k0 = t << 6;
        bf16x8 kv;
        int key = k0 + kKeyL;
        if (key < len) {
            kv = *(const bf16x8*)(base + (long long)key * 768 + 256 + h * HD + kgrp_ * 8);
        } else {
#pragma unroll
            for (int j = 0; j < 8; ++j) kv[j] = (__bf16)0.f;
        }
        stage[buf][kChunk] = kv;
        bf16x8 vv;
#pragma unroll
        for (int j = 0; j < 8; ++j) {
            int vkey = k0 + vKeyB + j;
            vv[j] = (vkey < len) ? base[(long long)vkey * 768 + 512 + h * HD + vDim]
                                 : (__bf16)0.f;
        }
        stage[buf][vChunk] = vv;
    };

    do_stage(0, 0);
    __syncthreads();

    for (int t = 0; t < nt; ++t) {
        int buf = t & 1;
        if (t + 1 < nt) do_stage(t + 1, buf ^ 1);

        int k0 = t << 6;
        bf16x8 kf0 = stage[buf][(0 * 4 + kg) * 17 + fr];
        bf16x8 kf1 = stage[buf][(1 * 4 + kg) * 17 + fr];
        bf16x8 kf2 = stage[buf][(2 * 4 + kg) * 17 + fr];
        bf16x8 kf3 = stage[buf][(3 * 4 + kg) * 17 + fr];

        f32x4 zero = {0.f, 0.f, 0.f, 0.f};
        f32x4 s0 = __builtin_amdgcn_mfma_f32_16x16x32_bf16(kf0, qfrag, zero, 0, 0, 0);
        f32x4 s1 = __builtin_amdgcn_mfma_f32_16x16x32_bf16(kf1, qfrag, zero, 0, 0, 0);
        f32x4 s2 = __builtin_amdgcn_mfma_f32_16x16x32_bf16(kf2, qfrag, zero, 0, 0, 0);
        f32x4 s3 = __builtin_amdgcn_mfma_f32_16x16x32_bf16(kf3, qfrag, zero, 0, 0, 0);

        float sc[16];
        int kb = k0 + kg * 8;
#pragma unroll
        for (int r = 0; r < 4; ++r) {
            sc[r]      = (kb + r < len)      ? s0[r] * scale : -3.0e38f;
            sc[4 + r]  = (kb + 4 + r < len)  ? s1[r] * scale : -3.0e38f;
            sc[8 + r]  = (kb + 32 + r < len) ? s2[r] * scale : -3.0e38f;
            sc[12 + r] = (kb + 36 + r < len) ? s3[r] * scale : -3.0e38f;
        }
        float tm = sc[0];
#pragma unroll
        for (int i = 1; i < 16; ++i) tm = fmaxf(tm, sc[i]);
        tm = fmaxf(tm, __shfl_xor(tm, 16));
        tm = fmaxf(tm, __shfl_xor(tm, 32));
        float mn = fmaxf(m, tm);
        float corr = __expf(m - mn);
        l *= corr;
#pragma unroll
        for (int r = 0; r < 4; ++r) { po0[r] *= corr; po1[r] *= corr; }
        m = mn;

        float p[16];
        float lsum = 0.f;
#pragma unroll
        for (int i = 0; i < 16; ++i) { p[i] = __expf(sc[i] - m); lsum += p[i]; }
        lsum += __shfl_xor(lsum, 16);
        lsum += __shfl_xor(lsum, 32);
        l += lsum;

        bf16x8 pf0, pf1;
#pragma unroll
        for (int j = 0; j < 8; ++j) { pf0[j] = (__bf16)p[j]; pf1[j] = (__bf16)p[8 + j]; }

        bf16x8 vf00 = stage[buf][272 + (0 * 4 + kg) * 17 + fr];
        bf16x8 vf01 = stage[buf][272 + (1 * 4 + kg) * 17 + fr];
        bf16x8 vf10 = stage[buf][272 + (2 * 4 + kg) * 17 + fr];
        bf16x8 vf11 = stage[buf][272 + (3 * 4 + kg) * 17 + fr];

        po0 = __builtin_amdgcn_mfma_f32_16x16x32_bf16(vf00, pf0, po0, 0, 0, 0);
        po0 = __builtin_amdgcn_mfma_f32_16x16x32_bf16(vf10, pf1, po0, 0, 0, 0);
        po1 = __builtin_amdgcn_mfma_f32_16x16x32_bf16(vf01, pf0, po1, 0, 0, 0);
        po1 = __builtin_amdgcn_mfma_f32_16x16x32_bf16(vf11, pf1, po1, 0, 0, 0);

        __syncthreads();
    }

    int q = q0 + wave * 16 + fr;
    if (q < len) {
        float inv = 1.f / l;
        __bf16* orow = o + ((long long)n * TLEN + q) * FEAT + h * HD;
        bf16x4 w0, w1;
#pragma unroll
        for (int r = 0; r < 4; ++r) {
            w0[r] = (__bf16)(po0[r] * inv);
            w1[r] = (__bf16)(po1[r] * inv);
        }
        *(bf16x4*)(orow + kg * 4) = w0;
        *(bf16x4*)(orow + 16 + kg * 4) = w1;
    }
}

// ---------------------------------------------------------------------------
// LayerNorm over last dim (256), one wave per valid token row.
// ---------------------------------------------------------------------------
__global__ __launch_bounds__(64) void ln_kernel(
    const float* __restrict__ tmp, float* __restrict__ x,
    const float* __restrict__ g, const float* __restrict__ b,
    const int* __restrict__ seqlen)
{
    int t = blockIdx.x, n = blockIdx.y;
    int len = (n & 1) ? 1 : seqlen[n >> 1];
    if (t >= len) return;
    int tid = threadIdx.x;
    const float* row = tmp + ((long long)n * TLEN + t) * FEAT;
    int f = tid * 4;
    float4 v = *(const float4*)(row + f);
    float s = v.x + v.y + v.z + v.w;
#pragma unroll
    for (int off = 32; off; off >>= 1) s += __shfl_down(s, off);
    float mu = __shfl(s, 0) * (1.f / 256.f);
    float dx = v.x - mu, dy = v.y - mu, dz = v.z - mu, dw = v.w - mu;
    float q = dx * dx + dy * dy + dz * dz + dw * dw;
#pragma unroll
    for (int off = 32; off; off >>= 1) q += __shfl_down(q, off);
    float var = __shfl(q, 0) * (1.f / 256.f);
    float r = rsqrtf(var + 1e-5f);
    float4 ov;
    ov.x = dx * r * g[f + 0] + b[f + 0];
    ov.y = dy * r * g[f + 1] + b[f + 1];
    ov.z = dz * r * g[f + 2] + b[f + 2];
    ov.w = dw * r * g[f + 3] + b[f + 3];
    *(float4*)(x + ((long long)n * TLEN + t) * FEAT + f) = ov;
}

// ---------------------------------------------------------------------------
// Masked mean-pool + output projection (x2 outputs). valid_cxr is int32.
// ---------------------------------------------------------------------------
__global__ __launch_bounds__(1024) void pool_out_kernel(
    const float* __restrict__ x, const float* __restrict__ W,
    const float* __restrict__ b, const int* __restrict__ seqlen,
    const int* __restrict__ valid_cxr, float* __restrict__ out)
{
    int n = blockIdx.x;
    int tid = threadIdx.x;
    int f = tid & 255;
    int tg = tid >> 8;
    int cnt = (n & 1) ? (valid_cxr[n >> 1] != 0 ? 1 : 0) : seqlen[n >> 1];

    __shared__ float part[4][FEAT];
    __shared__ float pooled[FEAT];

    const float* xb = x + (long long)n * TLEN * FEAT + f;
    float s0 = 0.f, s1 = 0.f;
    int t = tg;
    for (; t + 4 < cnt; t += 8) {
        s0 += xb[(long long)t * FEAT];
        s1 += xb[(long long)(t + 4) * FEAT];
    }
    if (t < cnt) s0 += xb[(long long)t * FEAT];
    part[tg][f] = s0 + s1;
    __syncthreads();
    if (tg == 0) {
        float v = part[0][f] + part[1][f] + part[2][f] + part[3][f];
        pooled[f] = cnt ? v / (float)cnt : 0.f;
    }
    __syncthreads();

    float acc = 0.f;
    const float* wcol = W + f;
#pragma unroll 8
    for (int k = tg * 64; k < tg * 64 + 64; ++k)
        acc += pooled[k] * wcol[(long long)k * FEAT];
    __syncthreads();
    part[tg][f] = acc;
    __syncthreads();
    if (tg == 0) {
        float v = part[0][f] + part[1][f] + part[2][f] + part[3][f] + b[f];
        out[(long long)n * FEAT + f] = v;
        out[NROWS * FEAT + (long long)n * FEAT + f] = v;
    }
}

// ---------------------------------------------------------------------------
extern "C" void kernel_launch(void* const* d_in, const int* in_sizes, int n_in,
                              void* d_out, int out_size, void* d_ws, size_t ws_size,
                              hipStream_t stream)
{
    const float* ehr_data = (const float*)d_in[0];
    const float* cxr_data = (const float*)d_in[1];
    const int*   seqlen   = (const int*)d_in[2];
    const int*   valid_cxr = (const int*)d_in[3];
    const float* ehr_w = (const float*)d_in[4];
    const float* ehr_b = (const float*)d_in[5];
    const float* cxr_w = (const float*)d_in[6];
    const float* cxr_b = (const float*)d_in[7];
    const float* modemb = (const float*)d_in[8];
    const float* pos    = (const float*)d_in[9];
    const float* qkv_w  = (const float*)d_in[10];
    const float* qkv_b  = (const float*)d_in[11];
    const float* aow    = (const float*)d_in[12];
    const float* aob    = (const float*)d_in[13];
    const float* ln1g   = (const float*)d_in[14];
    const float* ln1b   = (const float*)d_in[15];
    const float* ln2g   = (const float*)d_in[16];
    const float* ln2b   = (const float*)d_in[17];
    const float* ff1w   = (const float*)d_in[18];
    const float* ff1b   = (const float*)d_in[19];
    const float* ff2w   = (const float*)d_in[20];
    const float* ff2b   = (const float*)d_in[21];
    const float* outw   = (const float*)d_in[22];
    const float* outb   = (const float*)d_in[23];
    float* out = (float*)d_out;

    // ---- workspace layout (float slots) ----
    // x:    [0, 4104192)                 fp32 32*501*256
    // qkv:  [4104192, 10260480)          bf16 32*501*768 (12.3M elems)
    // obuf: [10260480, 12312576)         bf16 32*501*256
    // h:    overlays qkv+obuf exactly    bf16 32*501*1024 (both dead at ff1)
    // tmp:  [12312576, 16416768)         fp32 32*501*256
    // wb:   [16416768, 17661952)         bf16 weight pool (2,490,368 elems)
    // cpart:[17661952, 17727488)         fp32 16*16*256
    float* ws    = (float*)d_ws;
    float* x     = ws;
    __bf16* qkv  = (__bf16*)(ws + 4104192);
    __bf16* obuf = (__bf16*)(ws + 10260480);
    __bf16* h    = (__bf16*)(ws + 4104192);
    float* tmp   = ws + 12312576;
    __bf16* wb   = (__bf16*)(ws + 16416768);
    float* cpart = ws + 17661952;

    WPack p;
    unsigned off = 0;
    p.d[0] = { ehr_w, off, EHR_IN, FEAT, 512 };            off += 256 * 512;
    unsigned qkvOff = off;
    for (int l = 0; l < 3; ++l) { p.d[1 + l] = { qkv_w + (long long)l * FEAT * 768, off, FEAT, 768, FEAT };  off += 768 * FEAT; }
    unsigned aoOff = off;
    for (int l = 0; l < 3; ++l) { p.d[4 + l] = { aow + (long long)l * FEAT * FEAT, off, FEAT, FEAT, FEAT };  off += FEAT * FEAT; }
    unsigned ff1Off = off;
    for (int l = 0; l < 3; ++l) { p.d[7 + l] = { ff1w + (long long)l * FEAT * FFDIM, off, FEAT, FFDIM, FEAT }; off += FFDIM * FEAT; }
    unsigned ff2Off = off;
    for (int l = 0; l < 3; ++l) { p.d[10 + l] = { ff2w + (long long)l * FFDIM * FEAT, off, FFDIM, FEAT, FFDIM }; off += FEAT * FFDIM; }

    wconv_kernel<<<dim3(32, 32, 13), 256, 0, stream>>>(p, wb);

    // ehr projection -> even rows of x (fp32 in, fp32 out)
    gemm_mfma<0, 0><<<dim3(8, 4, 16), 256, 0, stream>>>(
        ehr_data, EHR_IN, (long long)MAXLEN * EHR_IN, MAXLEN,
        wb + 0, 512, EHR_IN,
        x, FEAT, (long long)2 * TLEN * FEAT,
        ehr_b, nullptr, 0, modemb, pos, seqlen, 0, F_POSEMB);
    // cxr projection -> odd rows token 0
    cxr_part<<<dim3(BATCH, 16), 256, 0, stream>>>(cxr_data, cxr_w, cpart);
    cxr_fin<<<BATCH, 256, 0, stream>>>(cpart, cxr_b, modemb + FEAT, pos, x);

    for (int l = 0; l < NLAYERS; ++l) {
        // qkv: fp32 x -> bf16 qkv
        gemm_mfma<0, 1><<<dim3(8, 12, 32), 256, 0, stream>>>(
            x, FEAT, (long long)TLEN * FEAT, TLEN,
            wb + qkvOff + (long long)l * 768 * FEAT, FEAT, FEAT,
            qkv, 3 * FEAT, (long long)TLEN * 3 * FEAT,
            qkv_b + (long long)l * 3 * FEAT, nullptr, 0, nullptr, nullptr, seqlen, 1, 0);

        attn_mfma<<<dim3(8, NHEAD, NROWS), 256, 0, stream>>>(qkv, obuf, seqlen);

        // attn out: bf16 obuf -> fp32 tmp (+ residual x)
        gemm_mfma<1, 0><<<dim3(8, 4, 32), 256, 0, stream>>>(
            obuf, FEAT, (long long)TLEN * FEAT, TLEN,
            wb + aoOff + (long long)l * FEAT * FEAT, FEAT, FEAT,
            tmp, FEAT, (long long)TLEN * FEAT,
            aob + (long long)l * FEAT, x, (long long)TLEN * FEAT, nullptr, nullptr, seqlen, 1, F_RESID);

        ln_kernel<<<dim3(TLEN, NROWS), 64, 0, stream>>>(
            tmp, x, ln1g + l * FEAT, ln1b + l * FEAT, seqlen);

        // ff1: fp32 x -> bf16 h (GELU)
        gemm_mfma<0, 1><<<dim3(8, 16, 32), 256, 0, stream>>>(
            x, FEAT, (long long)TLEN * FEAT, TLEN,
            wb + ff1Off + (long long)l * FFDIM * FEAT, FEAT, FEAT,
            h, FFDIM, (long long)TLEN * FFDIM,
            ff1b + (long long)l * FFDIM, nullptr, 0, nullptr, nullptr, seqlen, 1, F_GELU);

        // ff2: bf16 h -> fp32 tmp (+ residual x)
        gemm_mfma<1, 0><<<dim3(8, 4, 32), 256, 0, stream>>>(
            h, FFDIM, (long long)TLEN * FFDIM, TLEN,
            wb + ff2Off + (long long)l * FEAT * FFDIM, FFDIM, FFDIM,
            tmp, FEAT, (long long)TLEN * FEAT,
            ff2b + (long long)l * FEAT, x, (long long)TLEN * FEAT, nullptr, nullptr, seqlen, 1, F_RESID);

        ln_kernel<<<dim3(TLEN, NROWS), 64, 0, stream>>>(
            tmp, x, ln2g + l * FEAT, ln2b + l * FEAT, seqlen);
    }

    pool_out_kernel<<<NROWS, 1024, 0, stream>>>(x, outw, outb, seqlen, valid_cxr, out);
}